// Round 4
// baseline (1209.354 us; speedup 1.0000x reference)
//
#include <hip/hip_runtime.h>
#include <math.h>

#define BN_EPS 1e-5f

// ---------- helpers ----------

__device__ __forceinline__ float siluf(float v) {
    return v / (1.0f + __expf(-v));
}

// Cubic B-spline basis (4 funcs) on uniform knots g[j] = 2*j - 7, j=0..7.
__device__ __forceinline__ void bspline4(float x, float b[4]) {
    float u = (x + 7.0f) * 0.5f;
    float jf = floorf(u);
    float t = u - jf;
    float t2 = t * t, t3 = t2 * t;
    float omt = 1.0f - t;
    float v0 = t3 * (1.0f / 6.0f);
    float v1 = (-3.0f * t3 + 3.0f * t2 + 3.0f * t + 1.0f) * (1.0f / 6.0f);
    float v2 = (3.0f * t3 - 6.0f * t2 + 4.0f) * (1.0f / 6.0f);
    float v3 = omt * omt * omt * (1.0f / 6.0f);
    int j = (int)jf;
#pragma unroll
    for (int i = 0; i < 4; ++i) {
        int d = j - i;
        b[i] = (d == 0) ? v0 : (d == 1) ? v1 : (d == 2) ? v2 : (d == 3) ? v3 : 0.0f;
    }
}

// ---------- conv1: [1024,3,32,32] -> h1 [1024,32,31,31] + block partial stats ----------
// 1922 blocks x 256 thr. Wave w: o-half (w&1)*16, patch-half (w>>1)*256.
// Each lane owns 4 patches (stride 64) x 16 outputs.

__global__ __launch_bounds__(256, 2) void conv1_kernel(
        const float* __restrict__ x, const float* __restrict__ bw,
        const float* __restrict__ sw, float* __restrict__ h1,
        float* __restrict__ part) {
    __shared__ float Wl[12 * 32 * 8];  // [i][o][k(5 pad 8)] = 12 KB
    for (int j = threadIdx.x; j < 12 * 32 * 5; j += 256) {
        int i = j / 160;
        int r = j - i * 160;
        int o = r / 5;
        int k = r - o * 5;
        Wl[(i * 32 + o) * 8 + k] = (k == 0) ? bw[o * 12 + i]
                                            : sw[(o * 12 + i) * 4 + k - 1];
    }
    __syncthreads();

    int lane = threadIdx.x & 63;
    int wave = threadIdx.x >> 6;
    int og2 = wave & 1;        // o-half: outputs og2*16 .. og2*16+15
    int pg  = wave >> 1;       // patch-half
    int pbase = blockIdx.x * 512 + pg * 256 + lane;
    int pb[4], py[4], px[4];
#pragma unroll
    for (int r = 0; r < 4; ++r) {
        int p = pbase + 64 * r;
        pb[r] = p / 961;
        int q = p - pb[r] * 961;
        py[r] = q / 31;
        px[r] = q - py[r] * 31;
    }
    float acc[4][16];
#pragma unroll
    for (int r = 0; r < 4; ++r)
#pragma unroll
        for (int oo = 0; oo < 16; ++oo) acc[r][oo] = 0.0f;

#pragma unroll 2
    for (int i = 0; i < 12; ++i) {
        int c = i >> 2, dy = (i >> 1) & 1, dx = i & 1;
        float v[4];
#pragma unroll
        for (int r = 0; r < 4; ++r)
            v[r] = x[(pb[r] * 3 + c) * 1024 + (py[r] + dy) * 32 + px[r] + dx];
        float e[4][5];
#pragma unroll
        for (int r = 0; r < 4; ++r) {
            e[r][0] = siluf(v[r]);
            bspline4(v[r], &e[r][1]);
        }
#pragma unroll
        for (int oo = 0; oo < 16; ++oo) {
            const float* wp = &Wl[(i * 32 + og2 * 16 + oo) * 8];
            float4 w0 = *(const float4*)wp;
            float w4v = wp[4];
#pragma unroll
            for (int r = 0; r < 4; ++r) {
                acc[r][oo] += e[r][0] * w0.x + e[r][1] * w0.y + e[r][2] * w0.z
                            + e[r][3] * w0.w + e[r][4] * w4v;
            }
        }
    }

#pragma unroll
    for (int oo = 0; oo < 16; ++oo) {
        int o = og2 * 16 + oo;
#pragma unroll
        for (int r = 0; r < 4; ++r)
            h1[(pb[r] * 32 + o) * 961 + py[r] * 31 + px[r]] = acc[r][oo];
    }
    // per-wave partial stats -> deterministic scratch slot [2*o][blk*2 + pg]
#pragma unroll 1
    for (int oo = 0; oo < 16; ++oo) {
        float s = 0.f, s2 = 0.f;
#pragma unroll
        for (int r = 0; r < 4; ++r) {
            float a = acc[r][oo];
            s += a; s2 += a * a;
        }
#pragma unroll
        for (int off = 32; off > 0; off >>= 1) {
            s  += __shfl_down(s, off, 64);
            s2 += __shfl_down(s2, off, 64);
        }
        if (lane == 0) {
            int o = og2 * 16 + oo;
            int slot = blockIdx.x * 2 + pg;
            part[(size_t)(2 * o) * 3844 + slot]     = s;
            part[(size_t)(2 * o + 1) * 3844 + slot] = s2;
        }
    }
}

// ---------- conv2: pooled1 [1024,32,15,15] -> h2 [1024,64,14,14] + partial stats ----------
// grid (196, 4): 196 patch-blocks x 4 o-groups of 16 outputs.
// Block: 1024 patches (4 waves x 4 r x 64 lanes). Weights staged ONCE (40 KB),
// K-loop barrier-free, all weight reads wave-uniform broadcasts.

__global__ __launch_bounds__(256, 2) void conv2_kernel(
        const float* __restrict__ p1, const float* __restrict__ bw,
        const float* __restrict__ sw, float* __restrict__ h2,
        float* __restrict__ part) {
    __shared__ float W4[32 * 4 * 16 * 4];  // [c][s][oo][k=0..3] (sw), 32 KB
    __shared__ float Wb[32 * 4 * 16];      // [c][s][oo] (bw), 8 KB
    int obase = blockIdx.y * 16;
    for (int j = threadIdx.x; j < 8192; j += 256) {
        int k  = j & 3;
        int oo = (j >> 2) & 15;
        int s  = (j >> 6) & 3;
        int c  = j >> 8;
        W4[j] = sw[(obase + oo) * 512 + c * 16 + s * 4 + k];
    }
    for (int j = threadIdx.x; j < 2048; j += 256) {
        int oo = j & 15;
        int s  = (j >> 4) & 3;
        int c  = j >> 6;
        Wb[j] = bw[(obase + oo) * 128 + c * 4 + s];
    }
    __syncthreads();

    int lane = threadIdx.x & 63;
    int wave = threadIdx.x >> 6;
    int pbase = blockIdx.x * 1024 + wave * 256 + lane;
    int pb[4], qq[4], py[4], px[4];
#pragma unroll
    for (int r = 0; r < 4; ++r) {
        int p = pbase + 64 * r;
        pb[r] = p / 196;
        int q = p - pb[r] * 196;
        qq[r] = q;
        py[r] = q / 14;
        px[r] = q - py[r] * 14;
    }
    float acc[4][16];
#pragma unroll
    for (int r = 0; r < 4; ++r)
#pragma unroll
        for (int oo = 0; oo < 16; ++oo) acc[r][oo] = 0.0f;

#pragma unroll 2
    for (int c = 0; c < 32; ++c) {
        float v[4][4];
#pragma unroll
        for (int r = 0; r < 4; ++r) {
            const float* pc = p1 + (pb[r] * 32 + c) * 225 + py[r] * 15 + px[r];
#pragma unroll
            for (int s = 0; s < 4; ++s)
                v[r][s] = pc[(s >> 1) * 15 + (s & 1)];
        }
#pragma unroll 1
        for (int s = 0; s < 4; ++s) {
            float e[4][5];
#pragma unroll
            for (int r = 0; r < 4; ++r) {
                e[r][0] = siluf(v[r][s]);
                bspline4(v[r][s], &e[r][1]);
            }
            int cs = c * 4 + s;
#pragma unroll
            for (int oo = 0; oo < 16; ++oo) {
                float4 w4 = *(const float4*)&W4[(cs * 16 + oo) * 4];
                float wbv = Wb[cs * 16 + oo];
#pragma unroll
                for (int r = 0; r < 4; ++r) {
                    acc[r][oo] += e[r][0] * wbv + e[r][1] * w4.x + e[r][2] * w4.y
                                + e[r][3] * w4.z + e[r][4] * w4.w;
                }
            }
        }
    }

#pragma unroll
    for (int oo = 0; oo < 16; ++oo) {
        int o = obase + oo;
#pragma unroll
        for (int r = 0; r < 4; ++r)
            h2[(pb[r] * 64 + o) * 196 + qq[r]] = acc[r][oo];
    }
    // per-wave partial stats -> slot [2*o][blk*4 + wave]
#pragma unroll 1
    for (int oo = 0; oo < 16; ++oo) {
        float s = 0.f, s2 = 0.f;
#pragma unroll
        for (int r = 0; r < 4; ++r) {
            float a = acc[r][oo];
            s += a; s2 += a * a;
        }
#pragma unroll
        for (int off = 32; off > 0; off >>= 1) {
            s  += __shfl_down(s, off, 64);
            s2 += __shfl_down(s2, off, 64);
        }
        if (lane == 0) {
            int o = obase + oo;
            int slot = blockIdx.x * 4 + wave;
            part[(size_t)(2 * o) * 784 + slot]     = s;
            part[(size_t)(2 * o + 1) * 784 + slot] = s2;
        }
    }
}

// ---------- reduce per-block partials -> stats ----------

__global__ __launch_bounds__(256) void redstats_kernel(
        const float* __restrict__ part, float* __restrict__ stats, int nblk) {
    int p = blockIdx.x;
    const float* src = part + (size_t)p * nblk;
    float s = 0.f;
    for (int j = threadIdx.x; j < nblk; j += 256) s += src[j];
#pragma unroll
    for (int off = 32; off > 0; off >>= 1) s += __shfl_down(s, off, 64);
    __shared__ float ls[4];
    if ((threadIdx.x & 63) == 0) ls[threadIdx.x >> 6] = s;
    __syncthreads();
    if (threadIdx.x == 0) stats[p] = ls[0] + ls[1] + ls[2] + ls[3];
}

// ---------- fused BN + ReLU + 2x2 maxpool ----------

__global__ __launch_bounds__(256) void bnpool_kernel(
        const float* __restrict__ h, const float* __restrict__ stats,
        const float* __restrict__ g, const float* __restrict__ bb,
        float* __restrict__ out, int C, int H, int W, int PH, int PW,
        float invN, int total) {
    int t = blockIdx.x * 256 + threadIdx.x;
    if (t >= total) return;
    int px = t % PW;
    int py = (t / PW) % PH;
    int c  = (t / (PW * PH)) % C;
    int b  = t / (PW * PH * C);
    float mean = stats[2 * c] * invN;
    float var  = stats[2 * c + 1] * invN - mean * mean;
    float sc = rsqrtf(var + BN_EPS) * g[c];
    float sh = bb[c] - mean * sc;
    const float* hp = h + (((size_t)b * C + c) * H + 2 * py) * W + 2 * px;
    float v0 = fmaxf(hp[0] * sc + sh, 0.f);
    float v1 = fmaxf(hp[1] * sc + sh, 0.f);
    float v2 = fmaxf(hp[W] * sc + sh, 0.f);
    float v3 = fmaxf(hp[W + 1] * sc + sh, 0.f);
    out[t] = fmaxf(fmaxf(v0, v1), fmaxf(v2, v3));
}

// ---------- transpose fc1_w [64,3136] -> wT [3136,64] ----------

__global__ __launch_bounds__(256) void transpose_kernel(
        const float* __restrict__ w, float* __restrict__ wT) {
    int t = blockIdx.x * 256 + threadIdx.x;
    if (t >= 64 * 3136) return;
    int o = t & 63;
    int k = t >> 6;
    wT[(size_t)k * 64 + o] = w[(size_t)o * 3136 + k];
}

// ---------- fc1: pooled2 flat [1024,3136] @ wT -> z [1024,64] ----------

__global__ __launch_bounds__(256) void fc1_kernel(
        const float* __restrict__ xin, const float* __restrict__ wT,
        const float* __restrict__ bias, float* __restrict__ z) {
    __shared__ float xs[4 * 3136];
    __shared__ float red[4][4][64];
    int b0 = blockIdx.x * 4;
    for (int j = threadIdx.x; j < 4 * 3136; j += 256)
        xs[j] = xin[(size_t)b0 * 3136 + j];
    __syncthreads();
    int o = threadIdx.x & 63, q = threadIdx.x >> 6;
    float s0 = 0.f, s1 = 0.f, s2 = 0.f, s3 = 0.f;
    for (int j = q * 784; j < q * 784 + 784; ++j) {
        float wv = wT[(size_t)j * 64 + o];
        s0 += xs[j] * wv;
        s1 += xs[3136 + j] * wv;
        s2 += xs[2 * 3136 + j] * wv;
        s3 += xs[3 * 3136 + j] * wv;
    }
    red[0][q][o] = s0; red[1][q][o] = s1; red[2][q][o] = s2; red[3][q][o] = s3;
    __syncthreads();
    int bb = threadIdx.x >> 6;
    float tot = red[bb][0][o] + red[bb][1][o] + red[bb][2][o] + red[bb][3][o] + bias[o];
    z[((size_t)(b0 + bb)) * 64 + o] = tot;
}

// ---------- bn1d column stats over z [1024,64] ----------

__global__ __launch_bounds__(256) void colstats_kernel(
        const float* __restrict__ z, float* __restrict__ stats) {
    int c = blockIdx.x;
    float s = 0.f, s2 = 0.f;
    for (int b = threadIdx.x; b < 1024; b += 256) {
        float v = z[(size_t)b * 64 + c];
        s += v; s2 += v * v;
    }
#pragma unroll
    for (int off = 32; off > 0; off >>= 1) {
        s  += __shfl_down(s, off, 64);
        s2 += __shfl_down(s2, off, 64);
    }
    __shared__ float ls[8];
    int w = threadIdx.x >> 6;
    if ((threadIdx.x & 63) == 0) { ls[w * 2] = s; ls[w * 2 + 1] = s2; }
    __syncthreads();
    if (threadIdx.x == 0) {
        stats[2 * c]     = ls[0] + ls[2] + ls[4] + ls[6];
        stats[2 * c + 1] = ls[1] + ls[3] + ls[5] + ls[7];
    }
}

// ---------- final: bn1d + relu + fc2 -> out [1024,10] ----------

__global__ __launch_bounds__(256) void final_kernel(
        const float* __restrict__ z, const float* __restrict__ stats,
        const float* __restrict__ g, const float* __restrict__ bb,
        const float* __restrict__ w2, const float* __restrict__ b2,
        float* __restrict__ out) {
    int t = blockIdx.x * 256 + threadIdx.x;
    if (t >= 10240) return;
    int o = t % 10, b = t / 10;
    float acc = b2[o];
#pragma unroll 8
    for (int c = 0; c < 64; ++c) {
        float mean = stats[2 * c] * (1.0f / 1024.0f);
        float var  = stats[2 * c + 1] * (1.0f / 1024.0f) - mean * mean;
        float sc = rsqrtf(var + BN_EPS) * g[c];
        float a = fmaxf(z[(size_t)b * 64 + c] * sc + (bb[c] - mean * sc), 0.f);
        acc += a * w2[o * 64 + c];
    }
    out[t] = acc;
}

// ---------- launch ----------

extern "C" void kernel_launch(void* const* d_in, const int* in_sizes, int n_in,
                              void* d_out, int out_size, void* d_ws, size_t ws_size,
                              hipStream_t stream) {
    const float* x   = (const float*)d_in[0];
    const float* bw1 = (const float*)d_in[1];
    const float* sw1 = (const float*)d_in[2];
    const float* g1  = (const float*)d_in[3];
    const float* b1  = (const float*)d_in[4];
    const float* bw2 = (const float*)d_in[5];
    const float* sw2 = (const float*)d_in[6];
    const float* g2  = (const float*)d_in[7];
    const float* b2v = (const float*)d_in[8];
    const float* fw1 = (const float*)d_in[9];
    const float* fb1 = (const float*)d_in[10];
    const float* g3  = (const float*)d_in[11];
    const float* b3  = (const float*)d_in[12];
    const float* fw2 = (const float*)d_in[13];
    const float* fb2 = (const float*)d_in[14];
    float* out = (float*)d_out;

    char* ws = (char*)d_ws;
    // region A [0, 126 MB): h1 [1024,32,31,31]; later h2 [1024,64,14,14] (51.4 MB)
    //   + part2 tucked after h2 at +51,380,224 (0.4 MB) during conv2
    float* h1     = (float*)(ws);
    float* part2  = (float*)(ws + 51380224);
    // region B [126 MB, 155.5 MB): pooled1 [1024,32,15,15]; later pooled2.
    //   part1 aliases region B during conv1 (consumed by redstats before bnpool writes)
    float* pooled = (float*)(ws + 125960192);
    float* part1  = (float*)(ws + 125960192);
    float* z      = (float*)(ws + 155451392);   // [1024,64]
    float* wT     = (float*)(ws + 155713536);   // [3136,64]
    float* stats1 = (float*)(ws + 156516352);   // 64 floats
    float* stats2 = (float*)(ws + 156516608);   // 128 floats
    float* stats3 = (float*)(ws + 156517120);   // 128 floats

    transpose_kernel<<<(64 * 3136 + 255) / 256, 256, 0, stream>>>(fw1, wT);

    conv1_kernel<<<1922, 256, 0, stream>>>(x, bw1, sw1, h1, part1);
    redstats_kernel<<<64, 256, 0, stream>>>(part1, stats1, 3844);

    bnpool_kernel<<<(1024 * 32 * 225 + 255) / 256, 256, 0, stream>>>(
        h1, stats1, g1, b1, pooled, 32, 31, 31, 15, 15,
        1.0f / (1024.0f * 961.0f), 1024 * 32 * 225);

    float* h2 = h1;  // region A reuse
    {
        dim3 grid(196, 4);
        conv2_kernel<<<grid, 256, 0, stream>>>(pooled, bw2, sw2, h2, part2);
    }
    redstats_kernel<<<128, 256, 0, stream>>>(part2, stats2, 784);

    float* pooled2 = pooled;  // region B reuse
    bnpool_kernel<<<(1024 * 64 * 49 + 255) / 256, 256, 0, stream>>>(
        h2, stats2, g2, b2v, pooled2, 64, 14, 14, 7, 7,
        1.0f / (1024.0f * 196.0f), 1024 * 64 * 49);

    fc1_kernel<<<256, 256, 0, stream>>>(pooled2, wT, fb1, z);
    colstats_kernel<<<64, 256, 0, stream>>>(z, stats3);
    final_kernel<<<(10240 + 255) / 256, 256, 0, stream>>>(z, stats3, g3, b3, fw2, fb2, out);
}

// Round 5
// 571.782 us; speedup vs baseline: 2.1151x; 2.1151x over previous
//
#include <hip/hip_runtime.h>
#include <math.h>

#define BN_EPS 1e-5f

typedef __attribute__((ext_vector_type(8))) short bf16x8;
typedef __attribute__((ext_vector_type(4))) float f32x4;

// ---------- helpers ----------

__device__ __forceinline__ float siluf(float v) {
    return v / (1.0f + __expf(-v));
}

// fp32 -> bf16 (RNE) and back
__device__ __forceinline__ short f2bf(float f) {
    unsigned u = __float_as_uint(f);
    u += 0x7fffu + ((u >> 16) & 1u);
    return (short)(u >> 16);
}
__device__ __forceinline__ float bf2f(short h) {
    return __uint_as_float(((unsigned)(unsigned short)h) << 16);
}

// Cubic B-spline basis (4 funcs) on uniform knots g[j] = 2*j - 7, j=0..7.
__device__ __forceinline__ void bspline4(float x, float b[4]) {
    float u = (x + 7.0f) * 0.5f;
    float jf = floorf(u);
    float t = u - jf;
    float t2 = t * t, t3 = t2 * t;
    float omt = 1.0f - t;
    float v0 = t3 * (1.0f / 6.0f);
    float v1 = (-3.0f * t3 + 3.0f * t2 + 3.0f * t + 1.0f) * (1.0f / 6.0f);
    float v2 = (3.0f * t3 - 6.0f * t2 + 4.0f) * (1.0f / 6.0f);
    float v3 = omt * omt * omt * (1.0f / 6.0f);
    int j = (int)jf;
#pragma unroll
    for (int i = 0; i < 4; ++i) {
        int d = j - i;
        b[i] = (d == 0) ? v0 : (d == 1) ? v1 : (d == 2) ? v2 : (d == 3) ? v3 : 0.0f;
    }
}

// ---------- conv1 (r3-proven): [1024,3,32,32] -> h1 [1024,32,31,31] + partials ----------

__global__ __launch_bounds__(256, 4) void conv1_kernel(
        const float* __restrict__ x, const float* __restrict__ bw,
        const float* __restrict__ sw, float* __restrict__ h1,
        float* __restrict__ part) {
    __shared__ float Wl[12 * 32 * 8];
    for (int j = threadIdx.x; j < 12 * 32 * 5; j += 256) {
        int i = j / 160;
        int r = j - i * 160;
        int o = r / 5;
        int k = r - o * 5;
        Wl[(i * 32 + o) * 8 + k] = (k == 0) ? bw[o * 12 + i]
                                            : sw[(o * 12 + i) * 4 + k - 1];
    }
    __syncthreads();

    int lane = threadIdx.x & 63, og = threadIdx.x >> 6;
    int pbase = blockIdx.x * 256 + lane;
    int pb[4], py[4], px[4];
#pragma unroll
    for (int r = 0; r < 4; ++r) {
        int p = pbase + 64 * r;
        pb[r] = p / 961;
        int q = p - pb[r] * 961;
        py[r] = q / 31;
        px[r] = q - py[r] * 31;
    }
    float acc[4][8];
#pragma unroll
    for (int r = 0; r < 4; ++r)
#pragma unroll
        for (int oo = 0; oo < 8; ++oo) acc[r][oo] = 0.0f;

#pragma unroll 1
    for (int i = 0; i < 12; ++i) {
        int c = i >> 2, dy = (i >> 1) & 1, dx = i & 1;
        float v[4];
#pragma unroll
        for (int r = 0; r < 4; ++r)
            v[r] = x[(pb[r] * 3 + c) * 1024 + (py[r] + dy) * 32 + px[r] + dx];
        float e[4][5];
#pragma unroll
        for (int r = 0; r < 4; ++r) {
            e[r][0] = siluf(v[r]);
            bspline4(v[r], &e[r][1]);
        }
#pragma unroll
        for (int oo = 0; oo < 8; ++oo) {
            const float* wp = &Wl[(i * 32 + og * 8 + oo) * 8];
            float4 w0 = *(const float4*)wp;
            float w4v = wp[4];
#pragma unroll
            for (int r = 0; r < 4; ++r) {
                acc[r][oo] += e[r][0] * w0.x + e[r][1] * w0.y + e[r][2] * w0.z
                            + e[r][3] * w0.w + e[r][4] * w4v;
            }
        }
    }

#pragma unroll
    for (int oo = 0; oo < 8; ++oo) {
        int o = og * 8 + oo;
#pragma unroll
        for (int r = 0; r < 4; ++r)
            h1[(pb[r] * 32 + o) * 961 + py[r] * 31 + px[r]] = acc[r][oo];
    }
#pragma unroll 1
    for (int oo = 0; oo < 8; ++oo) {
        float s = 0.f, s2 = 0.f;
#pragma unroll
        for (int r = 0; r < 4; ++r) {
            float a = acc[r][oo];
            s += a; s2 += a * a;
        }
#pragma unroll
        for (int off = 32; off > 0; off >>= 1) {
            s  += __shfl_down(s, off, 64);
            s2 += __shfl_down(s2, off, 64);
        }
        if (lane == 0) {
            int o = og * 8 + oo;
            part[(size_t)(2 * o) * 3844 + blockIdx.x]     = s;
            part[(size_t)(2 * o + 1) * 3844 + blockIdx.x] = s2;
        }
    }
}

// ---------- conv2 (MFMA): pooled1 [1024,32,15,15] -> Pt [200704 patches][64 o] ----------
// GEMM C[200704,64] = E[.,640]_split_bf16 x W[640,64]_bf16.
// 3136 blocks x 256 thr; block = 64 patches x 64 outputs; 4 groups of 8 channels.
// LDS rows padded to 168 shorts (336 B) -> 2-way-max bank aliasing (free).

#define C2_LDW 168

__global__ __launch_bounds__(256, 2) void conv2_kernel(
        const float* __restrict__ p1, const float* __restrict__ bw,
        const float* __restrict__ sw, float* __restrict__ Pt,
        float* __restrict__ part) {
    __shared__ short Eh[64 * C2_LDW];
    __shared__ short El[64 * C2_LDW];
    __shared__ short Wt[64 * C2_LDW];

    int t = threadIdx.x;
    int lane = t & 63, wv = t >> 6;
    int quad = lane >> 4, l15 = lane & 15;

    // patch geometry for the two E-build cells this thread owns (m = t&63)
    int m_own = t & 63;
    int patch_own = blockIdx.x * 64 + m_own;
    int pb_own = patch_own / 196;
    int q_own  = patch_own - pb_own * 196;
    int py_own = q_own / 14;
    int px_own = q_own - py_own * 14;
    int cl0 = t >> 6;        // cells: (m_own, cl0) and (m_own, cl0+4)

    f32x4 acc[4];
#pragma unroll
    for (int mt = 0; mt < 4; ++mt) acc[mt] = (f32x4){0.f, 0.f, 0.f, 0.f};

#pragma unroll 1
    for (int g = 0; g < 4; ++g) {
        int c0 = g * 8;
        // ---- build E (hi/lo split) : 2 cells per thread ----
#pragma unroll
        for (int cc = 0; cc < 2; ++cc) {
            int cl = cl0 + cc * 4;
            const float* pc = p1 + ((size_t)pb_own * 32 + c0 + cl) * 225
                            + py_own * 15 + px_own;
            float vs[4];
            vs[0] = pc[0]; vs[1] = pc[1]; vs[2] = pc[15]; vs[3] = pc[16];
            float f[20];
#pragma unroll
            for (int s = 0; s < 4; ++s) {
                f[s * 5] = siluf(vs[s]);
                bspline4(vs[s], &f[s * 5 + 1]);
            }
            int* dh = (int*)&Eh[m_own * C2_LDW + cl * 20];
            int* dl = (int*)&El[m_own * C2_LDW + cl * 20];
#pragma unroll
            for (int i = 0; i < 10; ++i) {
                float a = f[2 * i], b = f[2 * i + 1];
                short ah = f2bf(a), bh = f2bf(b);
                float al = a - bf2f(ah), bl = b - bf2f(bh);
                short alo = f2bf(al), blo = f2bf(bl);
                dh[i] = (int)(unsigned short)ah | ((int)(unsigned short)bh << 16);
                dl[i] = (int)(unsigned short)alo | ((int)(unsigned short)blo << 16);
            }
        }
        // ---- stage W slice [n][k=160] : 2 cells per thread ----
#pragma unroll
        for (int cc = 0; cc < 2; ++cc) {
            int n = t & 63;
            int cl = (t >> 6) + cc * 4;
            int c = c0 + cl;
            float wvv[20];
#pragma unroll
            for (int s = 0; s < 4; ++s) {
                wvv[s * 5] = bw[n * 128 + c * 4 + s];
#pragma unroll
                for (int j = 0; j < 4; ++j)
                    wvv[s * 5 + 1 + j] = sw[n * 512 + c * 16 + s * 4 + j];
            }
            int* dw = (int*)&Wt[n * C2_LDW + cl * 20];
#pragma unroll
            for (int i = 0; i < 10; ++i) {
                short ah = f2bf(wvv[2 * i]), bh = f2bf(wvv[2 * i + 1]);
                dw[i] = (int)(unsigned short)ah | ((int)(unsigned short)bh << 16);
            }
        }
        __syncthreads();
        // ---- MFMA: wave wv -> outputs wv*16..+15, 4 M-tiles, 5 K-steps ----
#pragma unroll
        for (int ks = 0; ks < 5; ++ks) {
            int ko = ks * 32 + quad * 8;
            bf16x8 bfrag = *(const bf16x8*)&Wt[(wv * 16 + l15) * C2_LDW + ko];
#pragma unroll
            for (int mt = 0; mt < 4; ++mt) {
                bf16x8 ah = *(const bf16x8*)&Eh[(mt * 16 + l15) * C2_LDW + ko];
                bf16x8 al = *(const bf16x8*)&El[(mt * 16 + l15) * C2_LDW + ko];
                acc[mt] = __builtin_amdgcn_mfma_f32_16x16x32_bf16(ah, bfrag, acc[mt], 0, 0, 0);
                acc[mt] = __builtin_amdgcn_mfma_f32_16x16x32_bf16(al, bfrag, acc[mt], 0, 0, 0);
            }
        }
        __syncthreads();
    }

    // ---- store C tile: lane holds rows quad*4+reg, col = wv*16 + l15 ----
    int o = wv * 16 + l15;
#pragma unroll
    for (int mt = 0; mt < 4; ++mt) {
        int patch = blockIdx.x * 64 + mt * 16 + quad * 4;
        float* dst = Pt + (size_t)patch * 64 + o;
#pragma unroll
        for (int reg = 0; reg < 4; ++reg)
            dst[(size_t)reg * 64] = acc[mt][reg];
    }
    // ---- fused channel stats: sum over this block's 64 patches per o ----
    float s = 0.f, s2 = 0.f;
#pragma unroll
    for (int mt = 0; mt < 4; ++mt)
#pragma unroll
        for (int reg = 0; reg < 4; ++reg) {
            float a = acc[mt][reg];
            s += a; s2 += a * a;
        }
    s  += __shfl_down(s, 16, 64);
    s2 += __shfl_down(s2, 16, 64);
    s  += __shfl_down(s, 32, 64);
    s2 += __shfl_down(s2, 32, 64);
    if (lane < 16) {
        part[(size_t)(2 * o) * 3136 + blockIdx.x]     = s;
        part[(size_t)(2 * o + 1) * 3136 + blockIdx.x] = s2;
    }
}

// ---------- reduce per-block partials -> stats ----------

__global__ __launch_bounds__(256) void redstats_kernel(
        const float* __restrict__ part, float* __restrict__ stats, int nblk) {
    int p = blockIdx.x;
    const float* src = part + (size_t)p * nblk;
    float s = 0.f;
    for (int j = threadIdx.x; j < nblk; j += 256) s += src[j];
#pragma unroll
    for (int off = 32; off > 0; off >>= 1) s += __shfl_down(s, off, 64);
    __shared__ float ls[4];
    if ((threadIdx.x & 63) == 0) ls[threadIdx.x >> 6] = s;
    __syncthreads();
    if (threadIdx.x == 0) stats[p] = ls[0] + ls[1] + ls[2] + ls[3];
}

// ---------- stage-1 fused BN + ReLU + 2x2 maxpool ([b][c][H][W] layout) ----------

__global__ __launch_bounds__(256) void bnpool_kernel(
        const float* __restrict__ h, const float* __restrict__ stats,
        const float* __restrict__ g, const float* __restrict__ bb,
        float* __restrict__ out, int C, int H, int W, int PH, int PW,
        float invN, int total) {
    int t = blockIdx.x * 256 + threadIdx.x;
    if (t >= total) return;
    int px = t % PW;
    int py = (t / PW) % PH;
    int c  = (t / (PW * PH)) % C;
    int b  = t / (PW * PH * C);
    float mean = stats[2 * c] * invN;
    float var  = stats[2 * c + 1] * invN - mean * mean;
    float sc = rsqrtf(var + BN_EPS) * g[c];
    float sh = bb[c] - mean * sc;
    const float* hp = h + (((size_t)b * C + c) * H + 2 * py) * W + 2 * px;
    float v0 = fmaxf(hp[0] * sc + sh, 0.f);
    float v1 = fmaxf(hp[1] * sc + sh, 0.f);
    float v2 = fmaxf(hp[W] * sc + sh, 0.f);
    float v3 = fmaxf(hp[W + 1] * sc + sh, 0.f);
    out[t] = fmaxf(fmaxf(v0, v1), fmaxf(v2, v3));
}

// ---------- stage-2 BN + ReLU + pool from Pt [patch][64] -> pooled2 [b][q2*64+c] ----------

__global__ __launch_bounds__(256) void bnpool2_kernel(
        const float* __restrict__ Pt, const float* __restrict__ stats,
        const float* __restrict__ g, const float* __restrict__ bb,
        float* __restrict__ out) {
    int t = blockIdx.x * 256 + threadIdx.x;
    if (t >= 1024 * 49 * 64) return;
    int c  = t & 63;
    int q2 = (t >> 6) % 49;
    int b  = t / (49 * 64);
    float mean = stats[2 * c] * (1.0f / 200704.0f);
    float var  = stats[2 * c + 1] * (1.0f / 200704.0f) - mean * mean;
    float sc = rsqrtf(var + BN_EPS) * g[c];
    float sh = bb[c] - mean * sc;
    int py2 = q2 / 7, px2 = q2 - py2 * 7;
    int q = (py2 * 2) * 14 + px2 * 2;
    const float* p = Pt + ((size_t)b * 196 + q) * 64 + c;
    float v0 = fmaxf(p[0] * sc + sh, 0.f);
    float v1 = fmaxf(p[64] * sc + sh, 0.f);
    float v2 = fmaxf(p[14 * 64] * sc + sh, 0.f);
    float v3 = fmaxf(p[15 * 64] * sc + sh, 0.f);
    out[t] = fmaxf(fmaxf(v0, v1), fmaxf(v2, v3));
}

// ---------- transpose fc1_w into wT[(q2*64 + c)*64 + o] (matches pooled2 order) ----------

__global__ __launch_bounds__(256) void transpose_kernel(
        const float* __restrict__ w, float* __restrict__ wT) {
    int t = blockIdx.x * 256 + threadIdx.x;
    if (t >= 64 * 3136) return;
    int o = t & 63;
    int m = t >> 6;          // m = q2*64 + c
    int c = m & 63;
    int q2 = m >> 6;
    wT[(size_t)m * 64 + o] = w[(size_t)o * 3136 + c * 49 + q2];
}

// ---------- fc1: pooled2 flat [1024,3136] @ wT -> z [1024,64] ----------

__global__ __launch_bounds__(256) void fc1_kernel(
        const float* __restrict__ xin, const float* __restrict__ wT,
        const float* __restrict__ bias, float* __restrict__ z) {
    __shared__ float xs[4 * 3136];
    __shared__ float red[4][4][64];
    int b0 = blockIdx.x * 4;
    for (int j = threadIdx.x; j < 4 * 3136; j += 256)
        xs[j] = xin[(size_t)b0 * 3136 + j];
    __syncthreads();
    int o = threadIdx.x & 63, q = threadIdx.x >> 6;
    float s0 = 0.f, s1 = 0.f, s2 = 0.f, s3 = 0.f;
    for (int j = q * 784; j < q * 784 + 784; ++j) {
        float wv = wT[(size_t)j * 64 + o];
        s0 += xs[j] * wv;
        s1 += xs[3136 + j] * wv;
        s2 += xs[2 * 3136 + j] * wv;
        s3 += xs[3 * 3136 + j] * wv;
    }
    red[0][q][o] = s0; red[1][q][o] = s1; red[2][q][o] = s2; red[3][q][o] = s3;
    __syncthreads();
    int bb = threadIdx.x >> 6;
    float tot = red[bb][0][o] + red[bb][1][o] + red[bb][2][o] + red[bb][3][o] + bias[o];
    z[((size_t)(b0 + bb)) * 64 + o] = tot;
}

// ---------- bn1d column stats over z [1024,64] ----------

__global__ __launch_bounds__(256) void colstats_kernel(
        const float* __restrict__ z, float* __restrict__ stats) {
    int c = blockIdx.x;
    float s = 0.f, s2 = 0.f;
    for (int b = threadIdx.x; b < 1024; b += 256) {
        float v = z[(size_t)b * 64 + c];
        s += v; s2 += v * v;
    }
#pragma unroll
    for (int off = 32; off > 0; off >>= 1) {
        s  += __shfl_down(s, off, 64);
        s2 += __shfl_down(s2, off, 64);
    }
    __shared__ float ls[8];
    int w = threadIdx.x >> 6;
    if ((threadIdx.x & 63) == 0) { ls[w * 2] = s; ls[w * 2 + 1] = s2; }
    __syncthreads();
    if (threadIdx.x == 0) {
        stats[2 * c]     = ls[0] + ls[2] + ls[4] + ls[6];
        stats[2 * c + 1] = ls[1] + ls[3] + ls[5] + ls[7];
    }
}

// ---------- final: bn1d + relu + fc2 -> out [1024,10] ----------

__global__ __launch_bounds__(256) void final_kernel(
        const float* __restrict__ z, const float* __restrict__ stats,
        const float* __restrict__ g, const float* __restrict__ bb,
        const float* __restrict__ w2, const float* __restrict__ b2,
        float* __restrict__ out) {
    int t = blockIdx.x * 256 + threadIdx.x;
    if (t >= 10240) return;
    int o = t % 10, b = t / 10;
    float acc = b2[o];
#pragma unroll 8
    for (int c = 0; c < 64; ++c) {
        float mean = stats[2 * c] * (1.0f / 1024.0f);
        float var  = stats[2 * c + 1] * (1.0f / 1024.0f) - mean * mean;
        float sc = rsqrtf(var + BN_EPS) * g[c];
        float a = fmaxf(z[(size_t)b * 64 + c] * sc + (bb[c] - mean * sc), 0.f);
        acc += a * w2[o * 64 + c];
    }
    out[t] = acc;
}

// ---------- launch ----------

extern "C" void kernel_launch(void* const* d_in, const int* in_sizes, int n_in,
                              void* d_out, int out_size, void* d_ws, size_t ws_size,
                              hipStream_t stream) {
    const float* x   = (const float*)d_in[0];
    const float* bw1 = (const float*)d_in[1];
    const float* sw1 = (const float*)d_in[2];
    const float* g1  = (const float*)d_in[3];
    const float* b1  = (const float*)d_in[4];
    const float* bw2 = (const float*)d_in[5];
    const float* sw2 = (const float*)d_in[6];
    const float* g2  = (const float*)d_in[7];
    const float* b2v = (const float*)d_in[8];
    const float* fw1 = (const float*)d_in[9];
    const float* fb1 = (const float*)d_in[10];
    const float* g3  = (const float*)d_in[11];
    const float* b3  = (const float*)d_in[12];
    const float* fw2 = (const float*)d_in[13];
    const float* fb2 = (const float*)d_in[14];
    float* out = (float*)d_out;

    char* ws = (char*)d_ws;
    // region A [0, 126 MB): h1 [1024,32,31,31]; after bnpool1, reused as
    //   Pt [200704][64] (51.38 MB) + part2 at +51,380,224 (1.6 MB)
    float* h1     = (float*)(ws);
    float* Pt     = (float*)(ws);
    float* part2  = (float*)(ws + 51380224);
    // region B [126 MB, 155.5 MB): part1 during conv1 (consumed by redstats1),
    //   then pooled1 [1024,32,15,15], then pooled2 [1024,3136]
    float* pooled = (float*)(ws + 125960192);
    float* part1  = (float*)(ws + 125960192);
    float* z      = (float*)(ws + 155451392);   // [1024,64]
    float* wT     = (float*)(ws + 155713536);   // [3136,64]
    float* stats1 = (float*)(ws + 156516352);   // 64 floats
    float* stats2 = (float*)(ws + 156516608);   // 128 floats
    float* stats3 = (float*)(ws + 156517120);   // 128 floats

    transpose_kernel<<<(64 * 3136 + 255) / 256, 256, 0, stream>>>(fw1, wT);

    conv1_kernel<<<3844, 256, 0, stream>>>(x, bw1, sw1, h1, part1);
    redstats_kernel<<<64, 256, 0, stream>>>(part1, stats1, 3844);

    bnpool_kernel<<<(1024 * 32 * 225 + 255) / 256, 256, 0, stream>>>(
        h1, stats1, g1, b1, pooled, 32, 31, 31, 15, 15,
        1.0f / (1024.0f * 961.0f), 1024 * 32 * 225);

    conv2_kernel<<<3136, 256, 0, stream>>>(pooled, bw2, sw2, Pt, part2);
    redstats_kernel<<<128, 256, 0, stream>>>(part2, stats2, 3136);

    float* pooled2 = pooled;  // region B reuse (pooled1 dead after conv2)
    bnpool2_kernel<<<(1024 * 49 * 64 + 255) / 256, 256, 0, stream>>>(
        Pt, stats2, g2, b2v, pooled2);

    fc1_kernel<<<256, 256, 0, stream>>>(pooled2, wT, fb1, z);
    colstats_kernel<<<64, 256, 0, stream>>>(z, stats3);
    final_kernel<<<(10240 + 255) / 256, 256, 0, stream>>>(z, stats3, g3, b3, fw2, fb2, out);
}

// Round 6
// 540.582 us; speedup vs baseline: 2.2371x; 1.0577x over previous
//
#include <hip/hip_runtime.h>
#include <math.h>

#define BN_EPS 1e-5f
#define NSLOT1 8176   // conv1 1800*4 + border 244*4 wave-slots
#define NSLOT2 12544  // conv2 3136*4

typedef __attribute__((ext_vector_type(8))) short bf16x8;
typedef __attribute__((ext_vector_type(4))) float f32x4;

// ---------- helpers ----------

__device__ __forceinline__ float siluf(float v) {
    return v / (1.0f + __expf(-v));
}

__device__ __forceinline__ short f2bf(float f) {
    unsigned u = __float_as_uint(f);
    u += 0x7fffu + ((u >> 16) & 1u);
    return (short)(u >> 16);
}
__device__ __forceinline__ float bf2f(short h) {
    return __uint_as_float(((unsigned)(unsigned short)h) << 16);
}

// Cubic B-spline basis (4 funcs) on uniform knots g[j] = 2*j - 7.
__device__ __forceinline__ void bspline4(float x, float b[4]) {
    float u = (x + 7.0f) * 0.5f;
    float jf = floorf(u);
    float t = u - jf;
    float t2 = t * t, t3 = t2 * t;
    float omt = 1.0f - t;
    float v0 = t3 * (1.0f / 6.0f);
    float v1 = (-3.0f * t3 + 3.0f * t2 + 3.0f * t + 1.0f) * (1.0f / 6.0f);
    float v2 = (3.0f * t3 - 6.0f * t2 + 4.0f) * (1.0f / 6.0f);
    float v3 = omt * omt * omt * (1.0f / 6.0f);
    int j = (int)jf;
#pragma unroll
    for (int i = 0; i < 4; ++i) {
        int d = j - i;
        b[i] = (d == 0) ? v0 : (d == 1) ? v1 : (d == 2) ? v2 : (d == 3) ? v3 : 0.0f;
    }
}

// ---------- conv1 + fused raw maxpool + stats ----------
// 1800 blocks x 256 thr. Thread owns one 2x2 patch-quad x 16 channels (o-half).
// Writes pooled RAW max (BN+ReLU deferred to conv2: monotone since sc>0).
// pooled layout: [b][cell(225)][c(32)] - channel-contiguous, coalesced writes.

__global__ __launch_bounds__(256, 2) void conv1_kernel(
        const float* __restrict__ x, const float* __restrict__ bw,
        const float* __restrict__ sw, float* __restrict__ pooled,
        float* __restrict__ part) {
    __shared__ float Wl[12 * 32 * 8];
    for (int j = threadIdx.x; j < 12 * 32 * 5; j += 256) {
        int i = j / 160;
        int r = j - i * 160;
        int o = r / 5;
        int k = r - o * 5;
        Wl[(i * 32 + o) * 8 + k] = (k == 0) ? bw[o * 12 + i]
                                            : sw[(o * 12 + i) * 4 + k - 1];
    }
    __syncthreads();

    int lane = threadIdx.x & 63, wave = threadIdx.x >> 6;
    int tid = blockIdx.x * 256 + threadIdx.x;
    int ohalf = tid & 1;
    int quad = tid >> 1;               // 0..230399
    int b = quad / 225;
    int cell = quad - b * 225;
    int pm = cell / 15, pn = cell - pm * 15;
    int obase = ohalf * 16;

    float maxv[16], s[16], s2[16];
#pragma unroll
    for (int oo = 0; oo < 16; ++oo) { maxv[oo] = -3.0e38f; s[oo] = 0.f; s2[oo] = 0.f; }

#pragma unroll 1
    for (int pp = 0; pp < 4; ++pp) {
        int py = 2 * pm + (pp >> 1), px = 2 * pn + (pp & 1);
        float acc[16];
#pragma unroll
        for (int oo = 0; oo < 16; ++oo) acc[oo] = 0.f;
#pragma unroll 1
        for (int i = 0; i < 12; ++i) {
            int c = i >> 2, dy = (i >> 1) & 1, dx = i & 1;
            float v = x[(b * 3 + c) * 1024 + (py + dy) * 32 + px + dx];
            float e[5];
            e[0] = siluf(v);
            bspline4(v, &e[1]);
#pragma unroll
            for (int oo = 0; oo < 16; ++oo) {
                const float* wp = &Wl[(i * 32 + obase + oo) * 8];
                float4 w0 = *(const float4*)wp;
                acc[oo] += e[0] * w0.x + e[1] * w0.y + e[2] * w0.z
                         + e[3] * w0.w + e[4] * wp[4];
            }
        }
#pragma unroll
        for (int oo = 0; oo < 16; ++oo) {
            float a = acc[oo];
            maxv[oo] = fmaxf(maxv[oo], a);
            s[oo] += a;
            s2[oo] += a * a;
        }
    }

    // coalesced pooled-raw store: [b][cell][c]
    float* dst = pooled + ((size_t)b * 225 + cell) * 32 + obase;
#pragma unroll
    for (int oo = 0; oo < 16; ++oo) dst[oo] = maxv[oo];

    // parity-preserving wave reduce: lane0 <- even lanes (ohalf 0), lane1 <- odd
#pragma unroll 1
    for (int oo = 0; oo < 16; ++oo) {
        float a = s[oo], a2 = s2[oo];
#pragma unroll
        for (int off = 32; off >= 2; off >>= 1) {
            a  += __shfl_down(a, off, 64);
            a2 += __shfl_down(a2, off, 64);
        }
        if (lane < 2) {
            int o = lane * 16 + oo;
            int slot = blockIdx.x * 4 + wave;
            part[(size_t)(2 * o) * NSLOT1 + slot]     = a;
            part[(size_t)(2 * o + 1) * NSLOT1 + slot] = a2;
        }
    }
}

// ---------- border patches (py==30 or px==30): stats only ----------
// 244 blocks x 256 thr, one patch each (1024 images x 61 border patches).

__global__ __launch_bounds__(256, 2) void border_kernel(
        const float* __restrict__ x, const float* __restrict__ bw,
        const float* __restrict__ sw, float* __restrict__ part) {
    __shared__ float Wl[12 * 32 * 8];
    for (int j = threadIdx.x; j < 12 * 32 * 5; j += 256) {
        int i = j / 160;
        int r = j - i * 160;
        int o = r / 5;
        int k = r - o * 5;
        Wl[(i * 32 + o) * 8 + k] = (k == 0) ? bw[o * 12 + i]
                                            : sw[(o * 12 + i) * 4 + k - 1];
    }
    __syncthreads();

    int lane = threadIdx.x & 63, wave = threadIdx.x >> 6;
    int id = blockIdx.x * 256 + threadIdx.x;   // < 62464
    int b = id / 61, j = id - b * 61;
    int py = (j < 31) ? 30 : (j - 31);
    int px = (j < 31) ? j : 30;

    float acc[32];
#pragma unroll
    for (int o = 0; o < 32; ++o) acc[o] = 0.f;
#pragma unroll 1
    for (int i = 0; i < 12; ++i) {
        int c = i >> 2, dy = (i >> 1) & 1, dx = i & 1;
        float v = x[(b * 3 + c) * 1024 + (py + dy) * 32 + px + dx];
        float e[5];
        e[0] = siluf(v);
        bspline4(v, &e[1]);
#pragma unroll
        for (int o = 0; o < 32; ++o) {
            const float* wp = &Wl[(i * 32 + o) * 8];
            float4 w0 = *(const float4*)wp;
            acc[o] += e[0] * w0.x + e[1] * w0.y + e[2] * w0.z
                    + e[3] * w0.w + e[4] * wp[4];
        }
    }
#pragma unroll 1
    for (int o = 0; o < 32; ++o) {
        float a = acc[o], a2 = acc[o] * acc[o];
#pragma unroll
        for (int off = 32; off > 0; off >>= 1) {
            a  += __shfl_down(a, off, 64);
            a2 += __shfl_down(a2, off, 64);
        }
        if (lane == 0) {
            int slot = 7200 + blockIdx.x * 4 + wave;
            part[(size_t)(2 * o) * NSLOT1 + slot]     = a;
            part[(size_t)(2 * o + 1) * NSLOT1 + slot] = a2;
        }
    }
}

// ---------- conv2 (MFMA, wave-owns-M): pooled raw -> Pt [200704][64] ----------
// Applies stage-1 BN+ReLU inline during E-build.

#define C2_LDW 168

__global__ __launch_bounds__(256, 2) void conv2_kernel(
        const float* __restrict__ pooled, const float* __restrict__ stats1,
        const float* __restrict__ g1v, const float* __restrict__ b1v,
        const float* __restrict__ bw, const float* __restrict__ sw,
        float* __restrict__ Pt, float* __restrict__ part) {
    __shared__ short Eh[64 * C2_LDW];
    __shared__ short El[64 * C2_LDW];
    __shared__ short Wt[64 * C2_LDW];

    int t = threadIdx.x;
    int lane = t & 63, wv = t >> 6;
    int quad = lane >> 4, l15 = lane & 15;

    int m_own = t >> 2;        // patch row 0..63
    int clb   = t & 3;         // channel-in-group base (cl = clb + 4*cc)
    int patch_own = blockIdx.x * 64 + m_own;
    int pb_own = patch_own / 196;
    int q_own  = patch_own - pb_own * 196;
    int py_own = q_own / 14;
    int px_own = q_own - py_own * 14;
    const float* pwin = pooled + ((size_t)pb_own * 225 + py_own * 15 + px_own) * 32;
    const float invN1 = 1.0f / (1024.0f * 961.0f);

    f32x4 acc[4];
#pragma unroll
    for (int nt = 0; nt < 4; ++nt) acc[nt] = (f32x4){0.f, 0.f, 0.f, 0.f};

#pragma unroll 1
    for (int g = 0; g < 4; ++g) {
        int c0 = g * 8;
        // ---- build E rows (hi/lo split), 2 cells per thread ----
#pragma unroll
        for (int cc = 0; cc < 2; ++cc) {
            int cl = clb + cc * 4;
            int c = c0 + cl;
            float mean = stats1[2 * c] * invN1;
            float var  = stats1[2 * c + 1] * invN1 - mean * mean;
            float sc = rsqrtf(var + BN_EPS) * g1v[c];
            float sh = b1v[c] - mean * sc;
            float vs[4];
            vs[0] = pwin[c];           vs[1] = pwin[32 + c];
            vs[2] = pwin[15 * 32 + c]; vs[3] = pwin[16 * 32 + c];
            float f[20];
#pragma unroll
            for (int s = 0; s < 4; ++s) {
                float v = fmaxf(vs[s] * sc + sh, 0.f);
                f[s * 5] = siluf(v);
                bspline4(v, &f[s * 5 + 1]);
            }
            int* dh = (int*)&Eh[m_own * C2_LDW + cl * 20];
            int* dl = (int*)&El[m_own * C2_LDW + cl * 20];
#pragma unroll
            for (int i = 0; i < 10; ++i) {
                float a = f[2 * i], b = f[2 * i + 1];
                short ah = f2bf(a), bh = f2bf(b);
                short alo = f2bf(a - bf2f(ah)), blo = f2bf(b - bf2f(bh));
                dh[i] = (int)(unsigned short)ah | ((int)(unsigned short)bh << 16);
                dl[i] = (int)(unsigned short)alo | ((int)(unsigned short)blo << 16);
            }
        }
        // ---- stage W slice [n][k], 2 cells per thread (n = t>>2) ----
#pragma unroll
        for (int cc = 0; cc < 2; ++cc) {
            int n = t >> 2;
            int cl = clb + cc * 4;
            int c = c0 + cl;
            float wvv[20];
#pragma unroll
            for (int s = 0; s < 4; ++s) {
                wvv[s * 5] = bw[n * 128 + c * 4 + s];
#pragma unroll
                for (int k = 0; k < 4; ++k)
                    wvv[s * 5 + 1 + k] = sw[n * 512 + c * 16 + s * 4 + k];
            }
            int* dw = (int*)&Wt[n * C2_LDW + cl * 20];
#pragma unroll
            for (int i = 0; i < 10; ++i) {
                short ah = f2bf(wvv[2 * i]), bh = f2bf(wvv[2 * i + 1]);
                dw[i] = (int)(unsigned short)ah | ((int)(unsigned short)bh << 16);
            }
        }
        __syncthreads();
        // ---- MFMA: wave wv owns rows wv*16..+15, iterates 4 N-tiles ----
#pragma unroll
        for (int ks = 0; ks < 5; ++ks) {
            int ko = ks * 32 + quad * 8;
            bf16x8 ah = *(const bf16x8*)&Eh[(wv * 16 + l15) * C2_LDW + ko];
            bf16x8 al = *(const bf16x8*)&El[(wv * 16 + l15) * C2_LDW + ko];
#pragma unroll
            for (int nt = 0; nt < 4; ++nt) {
                bf16x8 bf = *(const bf16x8*)&Wt[(nt * 16 + l15) * C2_LDW + ko];
                acc[nt] = __builtin_amdgcn_mfma_f32_16x16x32_bf16(ah, bf, acc[nt], 0, 0, 0);
                acc[nt] = __builtin_amdgcn_mfma_f32_16x16x32_bf16(al, bf, acc[nt], 0, 0, 0);
            }
        }
        __syncthreads();
    }

    // ---- store: rows wv*16 + quad*4 + reg, cols nt*16 + l15 ----
    int rowb = blockIdx.x * 64 + wv * 16 + quad * 4;
#pragma unroll
    for (int nt = 0; nt < 4; ++nt) {
        int o = nt * 16 + l15;
#pragma unroll
        for (int reg = 0; reg < 4; ++reg)
            Pt[(size_t)(rowb + reg) * 64 + o] = acc[nt][reg];
    }
    // ---- fused stats over this wave's 16 rows ----
    float s[4], s2[4];
#pragma unroll
    for (int nt = 0; nt < 4; ++nt) {
        float a0 = acc[nt][0], a1 = acc[nt][1], a2v = acc[nt][2], a3 = acc[nt][3];
        s[nt]  = a0 + a1 + a2v + a3;
        s2[nt] = a0 * a0 + a1 * a1 + a2v * a2v + a3 * a3;
    }
#pragma unroll
    for (int nt = 0; nt < 4; ++nt) {
        s[nt]  += __shfl_down(s[nt], 16, 64);
        s2[nt] += __shfl_down(s2[nt], 16, 64);
        s[nt]  += __shfl_down(s[nt], 32, 64);
        s2[nt] += __shfl_down(s2[nt], 32, 64);
    }
    if (lane < 16) {
        int slot = blockIdx.x * 4 + wv;
#pragma unroll
        for (int nt = 0; nt < 4; ++nt) {
            int o = nt * 16 + l15;
            part[(size_t)(2 * o) * NSLOT2 + slot]     = s[nt];
            part[(size_t)(2 * o + 1) * NSLOT2 + slot] = s2[nt];
        }
    }
}

// ---------- reduce per-wave partials -> stats ----------

__global__ __launch_bounds__(256) void redstats_kernel(
        const float* __restrict__ part, float* __restrict__ stats, int nblk) {
    int p = blockIdx.x;
    const float* src = part + (size_t)p * nblk;
    float s = 0.f;
    for (int j = threadIdx.x; j < nblk; j += 256) s += src[j];
#pragma unroll
    for (int off = 32; off > 0; off >>= 1) s += __shfl_down(s, off, 64);
    __shared__ float ls[4];
    if ((threadIdx.x & 63) == 0) ls[threadIdx.x >> 6] = s;
    __syncthreads();
    if (threadIdx.x == 0) stats[p] = ls[0] + ls[1] + ls[2] + ls[3];
}

// ---------- stage-2 BN + ReLU + pool from Pt [patch][64] -> pooled2 [b][q2*64+c] ----------

__global__ __launch_bounds__(256) void bnpool2_kernel(
        const float* __restrict__ Pt, const float* __restrict__ stats,
        const float* __restrict__ g, const float* __restrict__ bb,
        float* __restrict__ out) {
    int t = blockIdx.x * 256 + threadIdx.x;
    if (t >= 1024 * 49 * 64) return;
    int c  = t & 63;
    int q2 = (t >> 6) % 49;
    int b  = t / (49 * 64);
    float mean = stats[2 * c] * (1.0f / 200704.0f);
    float var  = stats[2 * c + 1] * (1.0f / 200704.0f) - mean * mean;
    float sc = rsqrtf(var + BN_EPS) * g[c];
    float sh = bb[c] - mean * sc;
    int py2 = q2 / 7, px2 = q2 - py2 * 7;
    int q = (py2 * 2) * 14 + px2 * 2;
    const float* p = Pt + ((size_t)b * 196 + q) * 64 + c;
    float v0 = fmaxf(p[0] * sc + sh, 0.f);
    float v1 = fmaxf(p[64] * sc + sh, 0.f);
    float v2 = fmaxf(p[14 * 64] * sc + sh, 0.f);
    float v3 = fmaxf(p[15 * 64] * sc + sh, 0.f);
    out[t] = fmaxf(fmaxf(v0, v1), fmaxf(v2, v3));
}

// ---------- transpose fc1_w into wT[(q2*64 + c)*64 + o] ----------

__global__ __launch_bounds__(256) void transpose_kernel(
        const float* __restrict__ w, float* __restrict__ wT) {
    int t = blockIdx.x * 256 + threadIdx.x;
    if (t >= 64 * 3136) return;
    int o = t & 63;
    int m = t >> 6;          // m = q2*64 + c
    int c = m & 63;
    int q2 = m >> 6;
    wT[(size_t)m * 64 + o] = w[(size_t)o * 3136 + c * 49 + q2];
}

// ---------- fc1: pooled2 flat [1024,3136] @ wT -> z [1024,64] ----------

__global__ __launch_bounds__(256) void fc1_kernel(
        const float* __restrict__ xin, const float* __restrict__ wT,
        const float* __restrict__ bias, float* __restrict__ z) {
    __shared__ float xs[4 * 3136];
    __shared__ float red[4][4][64];
    int b0 = blockIdx.x * 4;
    for (int j = threadIdx.x; j < 4 * 3136; j += 256)
        xs[j] = xin[(size_t)b0 * 3136 + j];
    __syncthreads();
    int o = threadIdx.x & 63, q = threadIdx.x >> 6;
    float s0 = 0.f, s1 = 0.f, s2 = 0.f, s3 = 0.f;
    for (int j = q * 784; j < q * 784 + 784; ++j) {
        float wv = wT[(size_t)j * 64 + o];
        s0 += xs[j] * wv;
        s1 += xs[3136 + j] * wv;
        s2 += xs[2 * 3136 + j] * wv;
        s3 += xs[3 * 3136 + j] * wv;
    }
    red[0][q][o] = s0; red[1][q][o] = s1; red[2][q][o] = s2; red[3][q][o] = s3;
    __syncthreads();
    int bb = threadIdx.x >> 6;
    float tot = red[bb][0][o] + red[bb][1][o] + red[bb][2][o] + red[bb][3][o] + bias[o];
    z[((size_t)(b0 + bb)) * 64 + o] = tot;
}

// ---------- bn1d column stats over z [1024,64] ----------

__global__ __launch_bounds__(256) void colstats_kernel(
        const float* __restrict__ z, float* __restrict__ stats) {
    int c = blockIdx.x;
    float s = 0.f, s2 = 0.f;
    for (int b = threadIdx.x; b < 1024; b += 256) {
        float v = z[(size_t)b * 64 + c];
        s += v; s2 += v * v;
    }
#pragma unroll
    for (int off = 32; off > 0; off >>= 1) {
        s  += __shfl_down(s, off, 64);
        s2 += __shfl_down(s2, off, 64);
    }
    __shared__ float ls[8];
    int w = threadIdx.x >> 6;
    if ((threadIdx.x & 63) == 0) { ls[w * 2] = s; ls[w * 2 + 1] = s2; }
    __syncthreads();
    if (threadIdx.x == 0) {
        stats[2 * c]     = ls[0] + ls[2] + ls[4] + ls[6];
        stats[2 * c + 1] = ls[1] + ls[3] + ls[5] + ls[7];
    }
}

// ---------- final: bn1d + relu + fc2 -> out [1024,10] ----------

__global__ __launch_bounds__(256) void final_kernel(
        const float* __restrict__ z, const float* __restrict__ stats,
        const float* __restrict__ g, const float* __restrict__ bb,
        const float* __restrict__ w2, const float* __restrict__ b2,
        float* __restrict__ out) {
    int t = blockIdx.x * 256 + threadIdx.x;
    if (t >= 10240) return;
    int o = t % 10, b = t / 10;
    float acc = b2[o];
#pragma unroll 8
    for (int c = 0; c < 64; ++c) {
        float mean = stats[2 * c] * (1.0f / 1024.0f);
        float var  = stats[2 * c + 1] * (1.0f / 1024.0f) - mean * mean;
        float sc = rsqrtf(var + BN_EPS) * g[c];
        float a = fmaxf(z[(size_t)b * 64 + c] * sc + (bb[c] - mean * sc), 0.f);
        acc += a * w2[o * 64 + c];
    }
    out[t] = acc;
}

// ---------- launch ----------

extern "C" void kernel_launch(void* const* d_in, const int* in_sizes, int n_in,
                              void* d_out, int out_size, void* d_ws, size_t ws_size,
                              hipStream_t stream) {
    const float* x   = (const float*)d_in[0];
    const float* bw1 = (const float*)d_in[1];
    const float* sw1 = (const float*)d_in[2];
    const float* g1  = (const float*)d_in[3];
    const float* b1  = (const float*)d_in[4];
    const float* bw2 = (const float*)d_in[5];
    const float* sw2 = (const float*)d_in[6];
    const float* g2  = (const float*)d_in[7];
    const float* b2v = (const float*)d_in[8];
    const float* fw1 = (const float*)d_in[9];
    const float* fb1 = (const float*)d_in[10];
    const float* g3  = (const float*)d_in[11];
    const float* b3  = (const float*)d_in[12];
    const float* fw2 = (const float*)d_in[13];
    const float* fb2 = (const float*)d_in[14];
    float* out = (float*)d_out;

    char* ws = (char*)d_ws;
    // region A [0, 58 MB): part1 (2.1 MB) during conv1 (dead after redstats1),
    //   then Pt [200704][64] (51.38 MB) + part2 at +51,380,224 (6.4 MB)
    float* part1  = (float*)(ws);
    float* Pt     = (float*)(ws);
    float* part2  = (float*)(ws + 51380224);
    // region B: pooled raw [1024][225][32] (29.5 MB); later pooled2 [1024,3136]
    float* pooled = (float*)(ws + 125960192);
    float* z      = (float*)(ws + 155451392);   // [1024,64]
    float* wT     = (float*)(ws + 155713536);   // [3136,64]
    float* stats1 = (float*)(ws + 156516352);   // 64 floats
    float* stats2 = (float*)(ws + 156516608);   // 128 floats
    float* stats3 = (float*)(ws + 156517120);   // 128 floats

    transpose_kernel<<<(64 * 3136 + 255) / 256, 256, 0, stream>>>(fw1, wT);

    conv1_kernel<<<1800, 256, 0, stream>>>(x, bw1, sw1, pooled, part1);
    border_kernel<<<244, 256, 0, stream>>>(x, bw1, sw1, part1);
    redstats_kernel<<<64, 256, 0, stream>>>(part1, stats1, NSLOT1);

    conv2_kernel<<<3136, 256, 0, stream>>>(pooled, stats1, g1, b1,
                                           bw2, sw2, Pt, part2);
    redstats_kernel<<<128, 256, 0, stream>>>(part2, stats2, NSLOT2);

    float* pooled2 = pooled;  // region B reuse (pooled raw dead after conv2)
    bnpool2_kernel<<<(1024 * 49 * 64 + 255) / 256, 256, 0, stream>>>(
        Pt, stats2, g2, b2v, pooled2);

    fc1_kernel<<<256, 256, 0, stream>>>(pooled2, wT, fb1, z);
    colstats_kernel<<<64, 256, 0, stream>>>(z, stats3);
    final_kernel<<<(10240 + 255) / 256, 256, 0, stream>>>(z, stats3, g3, b3, fw2, fb2, out);
}

// Round 7
// 537.790 us; speedup vs baseline: 2.2487x; 1.0052x over previous
//
#include <hip/hip_runtime.h>
#include <math.h>

#define BN_EPS 1e-5f
#define NSLOT1 8176   // conv1 1800*4 + border 244*4 wave-slots
#define NSLOT2 12544  // conv2 3136*4

typedef __attribute__((ext_vector_type(8))) _Float16 f16x8;
typedef __attribute__((ext_vector_type(4))) float f32x4;

// ---------- helpers ----------

__device__ __forceinline__ float siluf(float v) {
    return v / (1.0f + __expf(-v));
}

// Cubic B-spline basis (4 funcs) on uniform knots g[j] = 2*j - 7.
__device__ __forceinline__ void bspline4(float x, float b[4]) {
    float u = (x + 7.0f) * 0.5f;
    float jf = floorf(u);
    float t = u - jf;
    float t2 = t * t, t3 = t2 * t;
    float omt = 1.0f - t;
    float v0 = t3 * (1.0f / 6.0f);
    float v1 = (-3.0f * t3 + 3.0f * t2 + 3.0f * t + 1.0f) * (1.0f / 6.0f);
    float v2 = (3.0f * t3 - 6.0f * t2 + 4.0f) * (1.0f / 6.0f);
    float v3 = omt * omt * omt * (1.0f / 6.0f);
    int j = (int)jf;
#pragma unroll
    for (int i = 0; i < 4; ++i) {
        int d = j - i;
        b[i] = (d == 0) ? v0 : (d == 1) ? v1 : (d == 2) ? v2 : (d == 3) ? v3 : 0.0f;
    }
}

// ---------- conv1 + fused raw maxpool + stats (r6-proven) ----------

__global__ __launch_bounds__(256, 2) void conv1_kernel(
        const float* __restrict__ x, const float* __restrict__ bw,
        const float* __restrict__ sw, float* __restrict__ pooled,
        float* __restrict__ part) {
    __shared__ float Wl[12 * 32 * 8];
    for (int j = threadIdx.x; j < 12 * 32 * 5; j += 256) {
        int i = j / 160;
        int r = j - i * 160;
        int o = r / 5;
        int k = r - o * 5;
        Wl[(i * 32 + o) * 8 + k] = (k == 0) ? bw[o * 12 + i]
                                            : sw[(o * 12 + i) * 4 + k - 1];
    }
    __syncthreads();

    int lane = threadIdx.x & 63, wave = threadIdx.x >> 6;
    int tid = blockIdx.x * 256 + threadIdx.x;
    int ohalf = tid & 1;
    int quad = tid >> 1;
    int b = quad / 225;
    int cell = quad - b * 225;
    int pm = cell / 15, pn = cell - pm * 15;
    int obase = ohalf * 16;

    float maxv[16], s[16], s2[16];
#pragma unroll
    for (int oo = 0; oo < 16; ++oo) { maxv[oo] = -3.0e38f; s[oo] = 0.f; s2[oo] = 0.f; }

#pragma unroll 1
    for (int pp = 0; pp < 4; ++pp) {
        int py = 2 * pm + (pp >> 1), px = 2 * pn + (pp & 1);
        float acc[16];
#pragma unroll
        for (int oo = 0; oo < 16; ++oo) acc[oo] = 0.f;
#pragma unroll 1
        for (int i = 0; i < 12; ++i) {
            int c = i >> 2, dy = (i >> 1) & 1, dx = i & 1;
            float v = x[(b * 3 + c) * 1024 + (py + dy) * 32 + px + dx];
            float e[5];
            e[0] = siluf(v);
            bspline4(v, &e[1]);
#pragma unroll
            for (int oo = 0; oo < 16; ++oo) {
                const float* wp = &Wl[(i * 32 + obase + oo) * 8];
                float4 w0 = *(const float4*)wp;
                acc[oo] += e[0] * w0.x + e[1] * w0.y + e[2] * w0.z
                         + e[3] * w0.w + e[4] * wp[4];
            }
        }
#pragma unroll
        for (int oo = 0; oo < 16; ++oo) {
            float a = acc[oo];
            maxv[oo] = fmaxf(maxv[oo], a);
            s[oo] += a;
            s2[oo] += a * a;
        }
    }

    float* dst = pooled + ((size_t)b * 225 + cell) * 32 + obase;
#pragma unroll
    for (int oo = 0; oo < 16; ++oo) dst[oo] = maxv[oo];

#pragma unroll 1
    for (int oo = 0; oo < 16; ++oo) {
        float a = s[oo], a2 = s2[oo];
#pragma unroll
        for (int off = 32; off >= 2; off >>= 1) {
            a  += __shfl_down(a, off, 64);
            a2 += __shfl_down(a2, off, 64);
        }
        if (lane < 2) {
            int o = lane * 16 + oo;
            int slot = blockIdx.x * 4 + wave;
            part[(size_t)(2 * o) * NSLOT1 + slot]     = a;
            part[(size_t)(2 * o + 1) * NSLOT1 + slot] = a2;
        }
    }
}

// ---------- border patches (py==30 or px==30): stats only ----------

__global__ __launch_bounds__(256, 2) void border_kernel(
        const float* __restrict__ x, const float* __restrict__ bw,
        const float* __restrict__ sw, float* __restrict__ part) {
    __shared__ float Wl[12 * 32 * 8];
    for (int j = threadIdx.x; j < 12 * 32 * 5; j += 256) {
        int i = j / 160;
        int r = j - i * 160;
        int o = r / 5;
        int k = r - o * 5;
        Wl[(i * 32 + o) * 8 + k] = (k == 0) ? bw[o * 12 + i]
                                            : sw[(o * 12 + i) * 4 + k - 1];
    }
    __syncthreads();

    int lane = threadIdx.x & 63, wave = threadIdx.x >> 6;
    int id = blockIdx.x * 256 + threadIdx.x;
    int b = id / 61, j = id - b * 61;
    int py = (j < 31) ? 30 : (j - 31);
    int px = (j < 31) ? j : 30;

    float acc[32];
#pragma unroll
    for (int o = 0; o < 32; ++o) acc[o] = 0.f;
#pragma unroll 1
    for (int i = 0; i < 12; ++i) {
        int c = i >> 2, dy = (i >> 1) & 1, dx = i & 1;
        float v = x[(b * 3 + c) * 1024 + (py + dy) * 32 + px + dx];
        float e[5];
        e[0] = siluf(v);
        bspline4(v, &e[1]);
#pragma unroll
        for (int o = 0; o < 32; ++o) {
            const float* wp = &Wl[(i * 32 + o) * 8];
            float4 w0 = *(const float4*)wp;
            acc[o] += e[0] * w0.x + e[1] * w0.y + e[2] * w0.z
                    + e[3] * w0.w + e[4] * wp[4];
        }
    }
#pragma unroll 1
    for (int o = 0; o < 32; ++o) {
        float a = acc[o], a2 = acc[o] * acc[o];
#pragma unroll
        for (int off = 32; off > 0; off >>= 1) {
            a  += __shfl_down(a, off, 64);
            a2 += __shfl_down(a2, off, 64);
        }
        if (lane == 0) {
            int slot = 7200 + blockIdx.x * 4 + wave;
            part[(size_t)(2 * o) * NSLOT1 + slot]     = a;
            part[(size_t)(2 * o + 1) * NSLOT1 + slot] = a2;
        }
    }
}

// ---------- pre-convert conv2 weights to f16, k-layout = c*20 + s*5 + f ----------

__global__ __launch_bounds__(256) void wconv16_kernel(
        const float* __restrict__ bw, const float* __restrict__ sw,
        _Float16* __restrict__ Wf) {
    int t = blockIdx.x * 256 + threadIdx.x;
    if (t >= 64 * 640) return;
    int n = t / 640;
    int k = t - n * 640;
    int c = k / 20;
    int r = k - c * 20;
    int s = r / 5;
    int f = r - s * 5;
    float val = (f == 0) ? bw[n * 128 + c * 4 + s]
                         : sw[n * 512 + c * 16 + s * 4 + (f - 1)];
    Wf[t] = (_Float16)val;
}

// ---------- conv2 (fp16 MFMA): pooled raw -> Pt [200704][64] ----------
// E built in fp16 (single MFMA, no split); W from pre-converted global f16
// (B-frags direct global b128 loads, L1-resident); Eh double-buffered -> one
// barrier per group. Stage-1 BN+ReLU applied inline in E-build.

#define C2_LDW 168

__global__ __launch_bounds__(256, 3) void conv2_kernel(
        const float* __restrict__ pooled, const float* __restrict__ stats1,
        const float* __restrict__ g1v, const float* __restrict__ b1v,
        const _Float16* __restrict__ Wf, float* __restrict__ Pt,
        float* __restrict__ part) {
    __shared__ _Float16 Eh[2][64 * C2_LDW];

    int t = threadIdx.x;
    int lane = t & 63, wv = t >> 6;
    int quad = lane >> 4, l15 = lane & 15;

    int cl = t & 7;          // channel within group (8 per group)
    int m0 = t >> 3;         // rows m0 and m0+32
    int pb[2], py[2], px[2];
#pragma unroll
    for (int cc = 0; cc < 2; ++cc) {
        int patch = blockIdx.x * 64 + m0 + 32 * cc;
        pb[cc] = patch / 196;
        int q = patch - pb[cc] * 196;
        py[cc] = q / 14;
        px[cc] = q - py[cc] * 14;
    }
    const float invN1 = 1.0f / (1024.0f * 961.0f);

    f32x4 acc[4];
#pragma unroll
    for (int nt = 0; nt < 4; ++nt) acc[nt] = (f32x4){0.f, 0.f, 0.f, 0.f};

#pragma unroll 1
    for (int g = 0; g < 4; ++g) {
        _Float16* Eb = Eh[g & 1];
        int c = g * 8 + cl;
        float mean = stats1[2 * c] * invN1;
        float var  = stats1[2 * c + 1] * invN1 - mean * mean;
        float sc = rsqrtf(var + BN_EPS) * g1v[c];
        float sh = b1v[c] - mean * sc;
        // ---- build E rows (fp16), 2 cells per thread ----
#pragma unroll
        for (int cc = 0; cc < 2; ++cc) {
            int m = m0 + 32 * cc;
            const float* pwin = pooled
                + ((size_t)pb[cc] * 225 + py[cc] * 15 + px[cc]) * 32;
            float vs[4];
            vs[0] = pwin[c];           vs[1] = pwin[32 + c];
            vs[2] = pwin[15 * 32 + c]; vs[3] = pwin[16 * 32 + c];
            float f[20];
#pragma unroll
            for (int s = 0; s < 4; ++s) {
                float v = fmaxf(vs[s] * sc + sh, 0.f);
                f[s * 5] = siluf(v);
                bspline4(v, &f[s * 5 + 1]);
            }
            int* dst = (int*)&Eb[m * C2_LDW + cl * 20];
#pragma unroll
            for (int i = 0; i < 10; ++i) {
                union { _Float16 h[2]; int i32; } u;
                u.h[0] = (_Float16)f[2 * i];
                u.h[1] = (_Float16)f[2 * i + 1];
                dst[i] = u.i32;
            }
        }
        __syncthreads();
        // ---- MFMA: wave wv owns M-tile wv, iterates 4 N-tiles ----
#pragma unroll
        for (int ks = 0; ks < 5; ++ks) {
            int ko = ks * 32 + quad * 8;
            f16x8 a = *(const f16x8*)&Eb[(wv * 16 + l15) * C2_LDW + ko];
#pragma unroll
            for (int nt = 0; nt < 4; ++nt) {
                f16x8 bf = *(const f16x8*)&Wf[(size_t)(nt * 16 + l15) * 640
                                              + g * 160 + ko];
                acc[nt] = __builtin_amdgcn_mfma_f32_16x16x32_f16(a, bf, acc[nt], 0, 0, 0);
            }
        }
    }

    // ---- store: rows wv*16 + quad*4 + reg, cols nt*16 + l15 ----
    int rowb = blockIdx.x * 64 + wv * 16 + quad * 4;
#pragma unroll
    for (int nt = 0; nt < 4; ++nt) {
        int o = nt * 16 + l15;
#pragma unroll
        for (int reg = 0; reg < 4; ++reg)
            Pt[(size_t)(rowb + reg) * 64 + o] = acc[nt][reg];
    }
    // ---- fused stats over this wave's 16 rows ----
    float s[4], s2[4];
#pragma unroll
    for (int nt = 0; nt < 4; ++nt) {
        float a0 = acc[nt][0], a1 = acc[nt][1], a2v = acc[nt][2], a3 = acc[nt][3];
        s[nt]  = a0 + a1 + a2v + a3;
        s2[nt] = a0 * a0 + a1 * a1 + a2v * a2v + a3 * a3;
    }
#pragma unroll
    for (int nt = 0; nt < 4; ++nt) {
        s[nt]  += __shfl_down(s[nt], 16, 64);
        s2[nt] += __shfl_down(s2[nt], 16, 64);
        s[nt]  += __shfl_down(s[nt], 32, 64);
        s2[nt] += __shfl_down(s2[nt], 32, 64);
    }
    if (lane < 16) {
        int slot = blockIdx.x * 4 + wv;
#pragma unroll
        for (int nt = 0; nt < 4; ++nt) {
            int o = nt * 16 + l15;
            part[(size_t)(2 * o) * NSLOT2 + slot]     = s[nt];
            part[(size_t)(2 * o + 1) * NSLOT2 + slot] = s2[nt];
        }
    }
}

// ---------- reduce per-wave partials -> stats ----------

__global__ __launch_bounds__(256) void redstats_kernel(
        const float* __restrict__ part, float* __restrict__ stats, int nblk) {
    int p = blockIdx.x;
    const float* src = part + (size_t)p * nblk;
    float s = 0.f;
    for (int j = threadIdx.x; j < nblk; j += 256) s += src[j];
#pragma unroll
    for (int off = 32; off > 0; off >>= 1) s += __shfl_down(s, off, 64);
    __shared__ float ls[4];
    if ((threadIdx.x & 63) == 0) ls[threadIdx.x >> 6] = s;
    __syncthreads();
    if (threadIdx.x == 0) stats[p] = ls[0] + ls[1] + ls[2] + ls[3];
}

// ---------- stage-2 BN + ReLU + pool from Pt [patch][64] -> pooled2 [b][q2*64+c] ----------

__global__ __launch_bounds__(256) void bnpool2_kernel(
        const float* __restrict__ Pt, const float* __restrict__ stats,
        const float* __restrict__ g, const float* __restrict__ bb,
        float* __restrict__ out) {
    int t = blockIdx.x * 256 + threadIdx.x;
    if (t >= 1024 * 49 * 64) return;
    int c  = t & 63;
    int q2 = (t >> 6) % 49;
    int b  = t / (49 * 64);
    float mean = stats[2 * c] * (1.0f / 200704.0f);
    float var  = stats[2 * c + 1] * (1.0f / 200704.0f) - mean * mean;
    float sc = rsqrtf(var + BN_EPS) * g[c];
    float sh = bb[c] - mean * sc;
    int py2 = q2 / 7, px2 = q2 - py2 * 7;
    int q = (py2 * 2) * 14 + px2 * 2;
    const float* p = Pt + ((size_t)b * 196 + q) * 64 + c;
    float v0 = fmaxf(p[0] * sc + sh, 0.f);
    float v1 = fmaxf(p[64] * sc + sh, 0.f);
    float v2 = fmaxf(p[14 * 64] * sc + sh, 0.f);
    float v3 = fmaxf(p[15 * 64] * sc + sh, 0.f);
    out[t] = fmaxf(fmaxf(v0, v1), fmaxf(v2, v3));
}

// ---------- transpose fc1_w into wT[(q2*64 + c)*64 + o] ----------

__global__ __launch_bounds__(256) void transpose_kernel(
        const float* __restrict__ w, float* __restrict__ wT) {
    int t = blockIdx.x * 256 + threadIdx.x;
    if (t >= 64 * 3136) return;
    int o = t & 63;
    int m = t >> 6;
    int c = m & 63;
    int q2 = m >> 6;
    wT[(size_t)m * 64 + o] = w[(size_t)o * 3136 + c * 49 + q2];
}

// ---------- fc1: pooled2 flat [1024,3136] @ wT -> z [1024,64] ----------

__global__ __launch_bounds__(256) void fc1_kernel(
        const float* __restrict__ xin, const float* __restrict__ wT,
        const float* __restrict__ bias, float* __restrict__ z) {
    __shared__ float xs[4 * 3136];
    __shared__ float red[4][4][64];
    int b0 = blockIdx.x * 4;
    for (int j = threadIdx.x; j < 4 * 3136; j += 256)
        xs[j] = xin[(size_t)b0 * 3136 + j];
    __syncthreads();
    int o = threadIdx.x & 63, q = threadIdx.x >> 6;
    float s0 = 0.f, s1 = 0.f, s2 = 0.f, s3 = 0.f;
    for (int j = q * 784; j < q * 784 + 784; ++j) {
        float wv = wT[(size_t)j * 64 + o];
        s0 += xs[j] * wv;
        s1 += xs[3136 + j] * wv;
        s2 += xs[2 * 3136 + j] * wv;
        s3 += xs[3 * 3136 + j] * wv;
    }
    red[0][q][o] = s0; red[1][q][o] = s1; red[2][q][o] = s2; red[3][q][o] = s3;
    __syncthreads();
    int bb = threadIdx.x >> 6;
    float tot = red[bb][0][o] + red[bb][1][o] + red[bb][2][o] + red[bb][3][o] + bias[o];
    z[((size_t)(b0 + bb)) * 64 + o] = tot;
}

// ---------- bn1d column stats over z [1024,64] ----------

__global__ __launch_bounds__(256) void colstats_kernel(
        const float* __restrict__ z, float* __restrict__ stats) {
    int c = blockIdx.x;
    float s = 0.f, s2 = 0.f;
    for (int b = threadIdx.x; b < 1024; b += 256) {
        float v = z[(size_t)b * 64 + c];
        s += v; s2 += v * v;
    }
#pragma unroll
    for (int off = 32; off > 0; off >>= 1) {
        s  += __shfl_down(s, off, 64);
        s2 += __shfl_down(s2, off, 64);
    }
    __shared__ float ls[8];
    int w = threadIdx.x >> 6;
    if ((threadIdx.x & 63) == 0) { ls[w * 2] = s; ls[w * 2 + 1] = s2; }
    __syncthreads();
    if (threadIdx.x == 0) {
        stats[2 * c]     = ls[0] + ls[2] + ls[4] + ls[6];
        stats[2 * c + 1] = ls[1] + ls[3] + ls[5] + ls[7];
    }
}

// ---------- final: bn1d + relu + fc2 -> out [1024,10] ----------

__global__ __launch_bounds__(256) void final_kernel(
        const float* __restrict__ z, const float* __restrict__ stats,
        const float* __restrict__ g, const float* __restrict__ bb,
        const float* __restrict__ w2, const float* __restrict__ b2,
        float* __restrict__ out) {
    int t = blockIdx.x * 256 + threadIdx.x;
    if (t >= 10240) return;
    int o = t % 10, b = t / 10;
    float acc = b2[o];
#pragma unroll 8
    for (int c = 0; c < 64; ++c) {
        float mean = stats[2 * c] * (1.0f / 1024.0f);
        float var  = stats[2 * c + 1] * (1.0f / 1024.0f) - mean * mean;
        float sc = rsqrtf(var + BN_EPS) * g[c];
        float a = fmaxf(z[(size_t)b * 64 + c] * sc + (bb[c] - mean * sc), 0.f);
        acc += a * w2[o * 64 + c];
    }
    out[t] = acc;
}

// ---------- launch ----------

extern "C" void kernel_launch(void* const* d_in, const int* in_sizes, int n_in,
                              void* d_out, int out_size, void* d_ws, size_t ws_size,
                              hipStream_t stream) {
    const float* x   = (const float*)d_in[0];
    const float* bw1 = (const float*)d_in[1];
    const float* sw1 = (const float*)d_in[2];
    const float* g1  = (const float*)d_in[3];
    const float* b1  = (const float*)d_in[4];
    const float* bw2 = (const float*)d_in[5];
    const float* sw2 = (const float*)d_in[6];
    const float* g2  = (const float*)d_in[7];
    const float* b2v = (const float*)d_in[8];
    const float* fw1 = (const float*)d_in[9];
    const float* fb1 = (const float*)d_in[10];
    const float* g3  = (const float*)d_in[11];
    const float* b3  = (const float*)d_in[12];
    const float* fw2 = (const float*)d_in[13];
    const float* fb2 = (const float*)d_in[14];
    float* out = (float*)d_out;

    char* ws = (char*)d_ws;
    // region A [0, 58 MB): part1 (2.1 MB) during conv1 (dead after redstats1),
    //   then Pt [200704][64] (51.38 MB) + part2 at +51,380,224 (6.4 MB)
    float* part1  = (float*)(ws);
    float* Pt     = (float*)(ws);
    float* part2  = (float*)(ws + 51380224);
    // Wf (80 KB) in the dead gap between region A and region B
    _Float16* Wf  = (_Float16*)(ws + 100000000);
    // region B: pooled raw [1024][225][32] (29.5 MB); later pooled2 [1024,3136]
    float* pooled = (float*)(ws + 125960192);
    float* z      = (float*)(ws + 155451392);   // [1024,64]
    float* wT     = (float*)(ws + 155713536);   // [3136,64]
    float* stats1 = (float*)(ws + 156516352);   // 64 floats
    float* stats2 = (float*)(ws + 156516608);   // 128 floats
    float* stats3 = (float*)(ws + 156517120);   // 128 floats

    transpose_kernel<<<(64 * 3136 + 255) / 256, 256, 0, stream>>>(fw1, wT);
    wconv16_kernel<<<160, 256, 0, stream>>>(bw2, sw2, Wf);

    conv1_kernel<<<1800, 256, 0, stream>>>(x, bw1, sw1, pooled, part1);
    border_kernel<<<244, 256, 0, stream>>>(x, bw1, sw1, part1);
    redstats_kernel<<<64, 256, 0, stream>>>(part1, stats1, NSLOT1);

    conv2_kernel<<<3136, 256, 0, stream>>>(pooled, stats1, g1, b1,
                                           Wf, Pt, part2);
    redstats_kernel<<<128, 256, 0, stream>>>(part2, stats2, NSLOT2);

    float* pooled2 = pooled;  // region B reuse (pooled raw dead after conv2)
    bnpool2_kernel<<<(1024 * 49 * 64 + 255) / 256, 256, 0, stream>>>(
        Pt, stats2, g2, b2v, pooled2);

    fc1_kernel<<<256, 256, 0, stream>>>(pooled2, wT, fb1, z);
    colstats_kernel<<<64, 256, 0, stream>>>(z, stats3);
    final_kernel<<<(10240 + 255) / 256, 256, 0, stream>>>(z, stats3, g3, b3, fw2, fb2, out);
}

// Round 8
// 513.320 us; speedup vs baseline: 2.3559x; 1.0477x over previous
//
#include <hip/hip_runtime.h>
#include <math.h>

#define BN_EPS 1e-5f
#define NSLOT1 8176   // conv1 1800*4 + border 244*4 wave-slots
#define NSLOT2 12544  // conv2 3136*4

typedef __attribute__((ext_vector_type(8))) _Float16 f16x8;
typedef __attribute__((ext_vector_type(4))) float f32x4;

// ---------- helpers ----------

__device__ __forceinline__ float siluf(float v) {
    return v / (1.0f + __expf(-v));
}

// Cubic B-spline basis (4 funcs) on uniform knots g[j] = 2*j - 7.
__device__ __forceinline__ void bspline4(float x, float b[4]) {
    float u = (x + 7.0f) * 0.5f;
    float jf = floorf(u);
    float t = u - jf;
    float t2 = t * t, t3 = t2 * t;
    float omt = 1.0f - t;
    float v0 = t3 * (1.0f / 6.0f);
    float v1 = (-3.0f * t3 + 3.0f * t2 + 3.0f * t + 1.0f) * (1.0f / 6.0f);
    float v2 = (3.0f * t3 - 6.0f * t2 + 4.0f) * (1.0f / 6.0f);
    float v3 = omt * omt * omt * (1.0f / 6.0f);
    int j = (int)jf;
#pragma unroll
    for (int i = 0; i < 4; ++i) {
        int d = j - i;
        b[i] = (d == 0) ? v0 : (d == 1) ? v1 : (d == 2) ? v2 : (d == 3) ? v3 : 0.0f;
    }
}

// ---------- conv1 + fused raw maxpool + stats ----------
// i-outer loop: each weight float4 read once per (i,oo), reused across the
// 4 pool positions -> 192 LDS b128 reads/thread (was 768).

__global__ __launch_bounds__(256, 4) void conv1_kernel(
        const float* __restrict__ x, const float* __restrict__ bw,
        const float* __restrict__ sw, float* __restrict__ pooled,
        float* __restrict__ part) {
    __shared__ float Wl[12 * 32 * 8];
    for (int j = threadIdx.x; j < 12 * 32 * 5; j += 256) {
        int i = j / 160;
        int r = j - i * 160;
        int o = r / 5;
        int k = r - o * 5;
        Wl[(i * 32 + o) * 8 + k] = (k == 0) ? bw[o * 12 + i]
                                            : sw[(o * 12 + i) * 4 + k - 1];
    }
    __syncthreads();

    int lane = threadIdx.x & 63, wave = threadIdx.x >> 6;
    int tid = blockIdx.x * 256 + threadIdx.x;
    int ohalf = tid & 1;
    int quad = tid >> 1;
    int b = quad / 225;
    int cell = quad - b * 225;
    int pm = cell / 15, pn = cell - pm * 15;
    int obase = ohalf * 16;

    float acc[4][16];
#pragma unroll
    for (int pp = 0; pp < 4; ++pp)
#pragma unroll
        for (int oo = 0; oo < 16; ++oo) acc[pp][oo] = 0.f;

#pragma unroll 1
    for (int i = 0; i < 12; ++i) {
        int c = i >> 2, dy = (i >> 1) & 1, dx = i & 1;
        const float* xb = x + (b * 3 + c) * 1024 + (2 * pm + dy) * 32 + 2 * pn + dx;
        float v[4];
        v[0] = xb[0]; v[1] = xb[1]; v[2] = xb[32]; v[3] = xb[33];
        float e[4][5];
#pragma unroll
        for (int pp = 0; pp < 4; ++pp) {
            e[pp][0] = siluf(v[pp]);
            bspline4(v[pp], &e[pp][1]);
        }
#pragma unroll
        for (int oo = 0; oo < 16; ++oo) {
            const float* wp = &Wl[(i * 32 + obase + oo) * 8];
            float4 w0 = *(const float4*)wp;
            float w4v = wp[4];
#pragma unroll
            for (int pp = 0; pp < 4; ++pp) {
                acc[pp][oo] += e[pp][0] * w0.x + e[pp][1] * w0.y + e[pp][2] * w0.z
                             + e[pp][3] * w0.w + e[pp][4] * w4v;
            }
        }
    }

    // register-light epilogue: per-oo pooled store + stats reduce
    float* dst = pooled + ((size_t)b * 225 + cell) * 32 + obase;
#pragma unroll 1
    for (int oo = 0; oo < 16; ++oo) {
        float a0 = acc[0][oo], a1 = acc[1][oo], a2 = acc[2][oo], a3 = acc[3][oo];
        dst[oo] = fmaxf(fmaxf(a0, a1), fmaxf(a2, a3));
        float s  = a0 + a1 + a2 + a3;
        float s2 = a0 * a0 + a1 * a1 + a2 * a2 + a3 * a3;
#pragma unroll
        for (int off = 32; off >= 2; off >>= 1) {
            s  += __shfl_down(s, off, 64);
            s2 += __shfl_down(s2, off, 64);
        }
        if (lane < 2) {
            int o = lane * 16 + oo;
            int slot = blockIdx.x * 4 + wave;
            part[(size_t)(2 * o) * NSLOT1 + slot]     = s;
            part[(size_t)(2 * o + 1) * NSLOT1 + slot] = s2;
        }
    }
}

// ---------- border patches (py==30 or px==30): stats only ----------

__global__ __launch_bounds__(256, 2) void border_kernel(
        const float* __restrict__ x, const float* __restrict__ bw,
        const float* __restrict__ sw, float* __restrict__ part) {
    __shared__ float Wl[12 * 32 * 8];
    for (int j = threadIdx.x; j < 12 * 32 * 5; j += 256) {
        int i = j / 160;
        int r = j - i * 160;
        int o = r / 5;
        int k = r - o * 5;
        Wl[(i * 32 + o) * 8 + k] = (k == 0) ? bw[o * 12 + i]
                                            : sw[(o * 12 + i) * 4 + k - 1];
    }
    __syncthreads();

    int lane = threadIdx.x & 63, wave = threadIdx.x >> 6;
    int id = blockIdx.x * 256 + threadIdx.x;
    int b = id / 61, j = id - b * 61;
    int py = (j < 31) ? 30 : (j - 31);
    int px = (j < 31) ? j : 30;

    float acc[32];
#pragma unroll
    for (int o = 0; o < 32; ++o) acc[o] = 0.f;
#pragma unroll 1
    for (int i = 0; i < 12; ++i) {
        int c = i >> 2, dy = (i >> 1) & 1, dx = i & 1;
        float v = x[(b * 3 + c) * 1024 + (py + dy) * 32 + px + dx];
        float e[5];
        e[0] = siluf(v);
        bspline4(v, &e[1]);
#pragma unroll
        for (int o = 0; o < 32; ++o) {
            const float* wp = &Wl[(i * 32 + o) * 8];
            float4 w0 = *(const float4*)wp;
            acc[o] += e[0] * w0.x + e[1] * w0.y + e[2] * w0.z
                    + e[3] * w0.w + e[4] * wp[4];
        }
    }
#pragma unroll 1
    for (int o = 0; o < 32; ++o) {
        float a = acc[o], a2 = acc[o] * acc[o];
#pragma unroll
        for (int off = 32; off > 0; off >>= 1) {
            a  += __shfl_down(a, off, 64);
            a2 += __shfl_down(a2, off, 64);
        }
        if (lane == 0) {
            int slot = 7200 + blockIdx.x * 4 + wave;
            part[(size_t)(2 * o) * NSLOT1 + slot]     = a;
            part[(size_t)(2 * o + 1) * NSLOT1 + slot] = a2;
        }
    }
}

// ---------- pre-convert conv2 weights to f16, k-layout = c*20 + s*5 + f ----------

__global__ __launch_bounds__(256) void wconv16_kernel(
        const float* __restrict__ bw, const float* __restrict__ sw,
        _Float16* __restrict__ Wf) {
    int t = blockIdx.x * 256 + threadIdx.x;
    if (t >= 64 * 640) return;
    int n = t / 640;
    int k = t - n * 640;
    int c = k / 20;
    int r = k - c * 20;
    int s = r / 5;
    int f = r - s * 5;
    float val = (f == 0) ? bw[n * 128 + c * 4 + s]
                         : sw[n * 512 + c * 16 + s * 4 + (f - 1)];
    Wf[t] = (_Float16)val;
}

// ---------- conv2 (fp16 MFMA, BARRIER-FREE): pooled raw -> Pt [200704][64] ----------
// Each wave builds its OWN 16 M-rows of E (lane -> row=wv*16+(lane>>3)(+8),
// ch=lane&7), so A-fragments only touch LDS written by the same wave:
// same-wave DS ordering replaces __syncthreads. Waves run fully independently.

#define C2_LDW 168

__global__ __launch_bounds__(256, 3) void conv2_kernel(
        const float* __restrict__ pooled, const float* __restrict__ stats1,
        const float* __restrict__ g1v, const float* __restrict__ b1v,
        const _Float16* __restrict__ Wf, float* __restrict__ Pt,
        float* __restrict__ part) {
    __shared__ _Float16 Eh[2][64 * C2_LDW];

    int t = threadIdx.x;
    int lane = t & 63, wv = t >> 6;
    int quad = lane >> 4, l15 = lane & 15;

    int cl = lane & 7;           // channel within group (8 per group)
    int rl = lane >> 3;          // 0..7; rows rl and rl+8 of this wave's tile
    int pb[2], py[2], px[2], m[2];
#pragma unroll
    for (int cc = 0; cc < 2; ++cc) {
        m[cc] = wv * 16 + rl + 8 * cc;
        int patch = blockIdx.x * 64 + m[cc];
        pb[cc] = patch / 196;
        int q = patch - pb[cc] * 196;
        py[cc] = q / 14;
        px[cc] = q - py[cc] * 14;
    }
    const float invN1 = 1.0f / (1024.0f * 961.0f);

    f32x4 acc[4];
#pragma unroll
    for (int nt = 0; nt < 4; ++nt) acc[nt] = (f32x4){0.f, 0.f, 0.f, 0.f};

#pragma unroll 1
    for (int g = 0; g < 4; ++g) {
        _Float16* Eb = Eh[g & 1];
        int c = g * 8 + cl;
        float mean = stats1[2 * c] * invN1;
        float var  = stats1[2 * c + 1] * invN1 - mean * mean;
        float sc = rsqrtf(var + BN_EPS) * g1v[c];
        float sh = b1v[c] - mean * sc;
        // ---- build this wave's 16 E rows (fp16), 2 cells per lane ----
#pragma unroll
        for (int cc = 0; cc < 2; ++cc) {
            const float* pwin = pooled
                + ((size_t)pb[cc] * 225 + py[cc] * 15 + px[cc]) * 32;
            float vs[4];
            vs[0] = pwin[c];           vs[1] = pwin[32 + c];
            vs[2] = pwin[15 * 32 + c]; vs[3] = pwin[16 * 32 + c];
            float f[20];
#pragma unroll
            for (int s = 0; s < 4; ++s) {
                float v = fmaxf(vs[s] * sc + sh, 0.f);
                f[s * 5] = siluf(v);
                bspline4(v, &f[s * 5 + 1]);
            }
            int* dst = (int*)&Eb[m[cc] * C2_LDW + cl * 20];
#pragma unroll
            for (int i = 0; i < 10; ++i) {
                union { _Float16 h[2]; int i32; } u;
                u.h[0] = (_Float16)f[2 * i];
                u.h[1] = (_Float16)f[2 * i + 1];
                dst[i] = u.i32;
            }
        }
        // ---- MFMA (no barrier: rows wv*16..+15 written by this wave) ----
#pragma unroll
        for (int ks = 0; ks < 5; ++ks) {
            int ko = ks * 32 + quad * 8;
            f16x8 a = *(const f16x8*)&Eb[(wv * 16 + l15) * C2_LDW + ko];
#pragma unroll
            for (int nt = 0; nt < 4; ++nt) {
                f16x8 bf = *(const f16x8*)&Wf[(size_t)(nt * 16 + l15) * 640
                                              + g * 160 + ko];
                acc[nt] = __builtin_amdgcn_mfma_f32_16x16x32_f16(a, bf, acc[nt], 0, 0, 0);
            }
        }
    }

    // ---- store: rows wv*16 + quad*4 + reg, cols nt*16 + l15 ----
    int rowb = blockIdx.x * 64 + wv * 16 + quad * 4;
#pragma unroll
    for (int nt = 0; nt < 4; ++nt) {
        int o = nt * 16 + l15;
#pragma unroll
        for (int reg = 0; reg < 4; ++reg)
            Pt[(size_t)(rowb + reg) * 64 + o] = acc[nt][reg];
    }
    // ---- fused stats over this wave's 16 rows ----
    float s[4], s2[4];
#pragma unroll
    for (int nt = 0; nt < 4; ++nt) {
        float a0 = acc[nt][0], a1 = acc[nt][1], a2v = acc[nt][2], a3 = acc[nt][3];
        s[nt]  = a0 + a1 + a2v + a3;
        s2[nt] = a0 * a0 + a1 * a1 + a2v * a2v + a3 * a3;
    }
#pragma unroll
    for (int nt = 0; nt < 4; ++nt) {
        s[nt]  += __shfl_down(s[nt], 16, 64);
        s2[nt] += __shfl_down(s2[nt], 16, 64);
        s[nt]  += __shfl_down(s[nt], 32, 64);
        s2[nt] += __shfl_down(s2[nt], 32, 64);
    }
    if (lane < 16) {
        int slot = blockIdx.x * 4 + wv;
#pragma unroll
        for (int nt = 0; nt < 4; ++nt) {
            int o = nt * 16 + l15;
            part[(size_t)(2 * o) * NSLOT2 + slot]     = s[nt];
            part[(size_t)(2 * o + 1) * NSLOT2 + slot] = s2[nt];
        }
    }
}

// ---------- reduce per-wave partials -> stats ----------

__global__ __launch_bounds__(256) void redstats_kernel(
        const float* __restrict__ part, float* __restrict__ stats, int nblk) {
    int p = blockIdx.x;
    const float* src = part + (size_t)p * nblk;
    float s = 0.f;
    for (int j = threadIdx.x; j < nblk; j += 256) s += src[j];
#pragma unroll
    for (int off = 32; off > 0; off >>= 1) s += __shfl_down(s, off, 64);
    __shared__ float ls[4];
    if ((threadIdx.x & 63) == 0) ls[threadIdx.x >> 6] = s;
    __syncthreads();
    if (threadIdx.x == 0) stats[p] = ls[0] + ls[1] + ls[2] + ls[3];
}

// ---------- stage-2 BN + ReLU + pool from Pt [patch][64] -> pooled2 [b][q2*64+c] ----------

__global__ __launch_bounds__(256) void bnpool2_kernel(
        const float* __restrict__ Pt, const float* __restrict__ stats,
        const float* __restrict__ g, const float* __restrict__ bb,
        float* __restrict__ out) {
    int t = blockIdx.x * 256 + threadIdx.x;
    if (t >= 1024 * 49 * 64) return;
    int c  = t & 63;
    int q2 = (t >> 6) % 49;
    int b  = t / (49 * 64);
    float mean = stats[2 * c] * (1.0f / 200704.0f);
    float var  = stats[2 * c + 1] * (1.0f / 200704.0f) - mean * mean;
    float sc = rsqrtf(var + BN_EPS) * g[c];
    float sh = bb[c] - mean * sc;
    int py2 = q2 / 7, px2 = q2 - py2 * 7;
    int q = (py2 * 2) * 14 + px2 * 2;
    const float* p = Pt + ((size_t)b * 196 + q) * 64 + c;
    float v0 = fmaxf(p[0] * sc + sh, 0.f);
    float v1 = fmaxf(p[64] * sc + sh, 0.f);
    float v2 = fmaxf(p[14 * 64] * sc + sh, 0.f);
    float v3 = fmaxf(p[15 * 64] * sc + sh, 0.f);
    out[t] = fmaxf(fmaxf(v0, v1), fmaxf(v2, v3));
}

// ---------- transpose fc1_w into wT[(q2*64 + c)*64 + o] ----------

__global__ __launch_bounds__(256) void transpose_kernel(
        const float* __restrict__ w, float* __restrict__ wT) {
    int t = blockIdx.x * 256 + threadIdx.x;
    if (t >= 64 * 3136) return;
    int o = t & 63;
    int m = t >> 6;
    int c = m & 63;
    int q2 = m >> 6;
    wT[(size_t)m * 64 + o] = w[(size_t)o * 3136 + c * 49 + q2];
}

// ---------- fc1: pooled2 flat [1024,3136] @ wT -> z [1024,64] ----------

__global__ __launch_bounds__(256) void fc1_kernel(
        const float* __restrict__ xin, const float* __restrict__ wT,
        const float* __restrict__ bias, float* __restrict__ z) {
    __shared__ float xs[4 * 3136];
    __shared__ float red[4][4][64];
    int b0 = blockIdx.x * 4;
    for (int j = threadIdx.x; j < 4 * 3136; j += 256)
        xs[j] = xin[(size_t)b0 * 3136 + j];
    __syncthreads();
    int o = threadIdx.x & 63, q = threadIdx.x >> 6;
    float s0 = 0.f, s1 = 0.f, s2 = 0.f, s3 = 0.f;
    for (int j = q * 784; j < q * 784 + 784; ++j) {
        float wv = wT[(size_t)j * 64 + o];
        s0 += xs[j] * wv;
        s1 += xs[3136 + j] * wv;
        s2 += xs[2 * 3136 + j] * wv;
        s3 += xs[3 * 3136 + j] * wv;
    }
    red[0][q][o] = s0; red[1][q][o] = s1; red[2][q][o] = s2; red[3][q][o] = s3;
    __syncthreads();
    int bb = threadIdx.x >> 6;
    float tot = red[bb][0][o] + red[bb][1][o] + red[bb][2][o] + red[bb][3][o] + bias[o];
    z[((size_t)(b0 + bb)) * 64 + o] = tot;
}

// ---------- bn1d column stats over z [1024,64] ----------

__global__ __launch_bounds__(256) void colstats_kernel(
        const float* __restrict__ z, float* __restrict__ stats) {
    int c = blockIdx.x;
    float s = 0.f, s2 = 0.f;
    for (int b = threadIdx.x; b < 1024; b += 256) {
        float v = z[(size_t)b * 64 + c];
        s += v; s2 += v * v;
    }
#pragma unroll
    for (int off = 32; off > 0; off >>= 1) {
        s  += __shfl_down(s, off, 64);
        s2 += __shfl_down(s2, off, 64);
    }
    __shared__ float ls[8];
    int w = threadIdx.x >> 6;
    if ((threadIdx.x & 63) == 0) { ls[w * 2] = s; ls[w * 2 + 1] = s2; }
    __syncthreads();
    if (threadIdx.x == 0) {
        stats[2 * c]     = ls[0] + ls[2] + ls[4] + ls[6];
        stats[2 * c + 1] = ls[1] + ls[3] + ls[5] + ls[7];
    }
}

// ---------- final: bn1d + relu + fc2 -> out [1024,10] ----------

__global__ __launch_bounds__(256) void final_kernel(
        const float* __restrict__ z, const float* __restrict__ stats,
        const float* __restrict__ g, const float* __restrict__ bb,
        const float* __restrict__ w2, const float* __restrict__ b2,
        float* __restrict__ out) {
    int t = blockIdx.x * 256 + threadIdx.x;
    if (t >= 10240) return;
    int o = t % 10, b = t / 10;
    float acc = b2[o];
#pragma unroll 8
    for (int c = 0; c < 64; ++c) {
        float mean = stats[2 * c] * (1.0f / 1024.0f);
        float var  = stats[2 * c + 1] * (1.0f / 1024.0f) - mean * mean;
        float sc = rsqrtf(var + BN_EPS) * g[c];
        float a = fmaxf(z[(size_t)b * 64 + c] * sc + (bb[c] - mean * sc), 0.f);
        acc += a * w2[o * 64 + c];
    }
    out[t] = acc;
}

// ---------- launch ----------

extern "C" void kernel_launch(void* const* d_in, const int* in_sizes, int n_in,
                              void* d_out, int out_size, void* d_ws, size_t ws_size,
                              hipStream_t stream) {
    const float* x   = (const float*)d_in[0];
    const float* bw1 = (const float*)d_in[1];
    const float* sw1 = (const float*)d_in[2];
    const float* g1  = (const float*)d_in[3];
    const float* b1  = (const float*)d_in[4];
    const float* bw2 = (const float*)d_in[5];
    const float* sw2 = (const float*)d_in[6];
    const float* g2  = (const float*)d_in[7];
    const float* b2v = (const float*)d_in[8];
    const float* fw1 = (const float*)d_in[9];
    const float* fb1 = (const float*)d_in[10];
    const float* g3  = (const float*)d_in[11];
    const float* b3  = (const float*)d_in[12];
    const float* fw2 = (const float*)d_in[13];
    const float* fb2 = (const float*)d_in[14];
    float* out = (float*)d_out;

    char* ws = (char*)d_ws;
    // region A [0, 58 MB): part1 (2.1 MB) during conv1 (dead after redstats1),
    //   then Pt [200704][64] (51.38 MB) + part2 at +51,380,224 (6.4 MB)
    float* part1  = (float*)(ws);
    float* Pt     = (float*)(ws);
    float* part2  = (float*)(ws + 51380224);
    // Wf (80 KB) in the dead gap between region A and region B
    _Float16* Wf  = (_Float16*)(ws + 100000000);
    // region B: pooled raw [1024][225][32] (29.5 MB); later pooled2 [1024,3136]
    float* pooled = (float*)(ws + 125960192);
    float* z      = (float*)(ws + 155451392);   // [1024,64]
    float* wT     = (float*)(ws + 155713536);   // [3136,64]
    float* stats1 = (float*)(ws + 156516352);   // 64 floats
    float* stats2 = (float*)(ws + 156516608);   // 128 floats
    float* stats3 = (float*)(ws + 156517120);   // 128 floats

    transpose_kernel<<<(64 * 3136 + 255) / 256, 256, 0, stream>>>(fw1, wT);
    wconv16_kernel<<<160, 256, 0, stream>>>(bw2, sw2, Wf);

    conv1_kernel<<<1800, 256, 0, stream>>>(x, bw1, sw1, pooled, part1);
    border_kernel<<<244, 256, 0, stream>>>(x, bw1, sw1, part1);
    redstats_kernel<<<64, 256, 0, stream>>>(part1, stats1, NSLOT1);

    conv2_kernel<<<3136, 256, 0, stream>>>(pooled, stats1, g1, b1,
                                           Wf, Pt, part2);
    redstats_kernel<<<128, 256, 0, stream>>>(part2, stats2, NSLOT2);

    float* pooled2 = pooled;  // region B reuse (pooled raw dead after conv2)
    bnpool2_kernel<<<(1024 * 49 * 64 + 255) / 256, 256, 0, stream>>>(
        Pt, stats2, g2, b2v, pooled2);

    fc1_kernel<<<256, 256, 0, stream>>>(pooled2, wT, fb1, z);
    colstats_kernel<<<64, 256, 0, stream>>>(z, stats3);
    final_kernel<<<(10240 + 255) / 256, 256, 0, stream>>>(z, stats3, g3, b3, fw2, fb2, out);
}

// Round 9
// 485.876 us; speedup vs baseline: 2.4890x; 1.0565x over previous
//
#include <hip/hip_runtime.h>
#include <math.h>

#define BN_EPS 1e-5f
#define NSLOT1 8176   // conv1 1800*4 + border 244*4 wave-slots
#define NSLOT2 12544  // conv2 3136*4

typedef __attribute__((ext_vector_type(8))) _Float16 f16x8;
typedef __attribute__((ext_vector_type(4))) float f32x4;

// ---------- helpers ----------

__device__ __forceinline__ float siluf(float v) {
    return v / (1.0f + __expf(-v));
}

// Cubic B-spline basis (4 funcs) on uniform knots g[j] = 2*j - 7.
__device__ __forceinline__ void bspline4(float x, float b[4]) {
    float u = (x + 7.0f) * 0.5f;
    float jf = floorf(u);
    float t = u - jf;
    float t2 = t * t, t3 = t2 * t;
    float omt = 1.0f - t;
    float v0 = t3 * (1.0f / 6.0f);
    float v1 = (-3.0f * t3 + 3.0f * t2 + 3.0f * t + 1.0f) * (1.0f / 6.0f);
    float v2 = (3.0f * t3 - 6.0f * t2 + 4.0f) * (1.0f / 6.0f);
    float v3 = omt * omt * omt * (1.0f / 6.0f);
    int j = (int)jf;
#pragma unroll
    for (int i = 0; i < 4; ++i) {
        int d = j - i;
        b[i] = (d == 0) ? v0 : (d == 1) ? v1 : (d == 2) ? v2 : (d == 3) ? v3 : 0.0f;
    }
}

// ---------- conv1 + fused raw maxpool + stats ----------
// i-outer with one-window lookahead prefetch of the 4 x-values.

__global__ __launch_bounds__(256, 4) void conv1_kernel(
        const float* __restrict__ x, const float* __restrict__ bw,
        const float* __restrict__ sw, float* __restrict__ pooled,
        float* __restrict__ part) {
    __shared__ float Wl[12 * 32 * 8];
    for (int j = threadIdx.x; j < 12 * 32 * 5; j += 256) {
        int i = j / 160;
        int r = j - i * 160;
        int o = r / 5;
        int k = r - o * 5;
        Wl[(i * 32 + o) * 8 + k] = (k == 0) ? bw[o * 12 + i]
                                            : sw[(o * 12 + i) * 4 + k - 1];
    }
    __syncthreads();

    int lane = threadIdx.x & 63, wave = threadIdx.x >> 6;
    int tid = blockIdx.x * 256 + threadIdx.x;
    int ohalf = tid & 1;
    int quad = tid >> 1;
    int b = quad / 225;
    int cell = quad - b * 225;
    int pm = cell / 15, pn = cell - pm * 15;
    int obase = ohalf * 16;

    float acc[4][16];
#pragma unroll
    for (int pp = 0; pp < 4; ++pp)
#pragma unroll
        for (int oo = 0; oo < 16; ++oo) acc[pp][oo] = 0.f;

    const float* xb0 = x + (b * 3) * 1024 + (2 * pm) * 32 + 2 * pn;
    float v0, v1, v2, v3;
    v0 = xb0[0]; v1 = xb0[1]; v2 = xb0[32]; v3 = xb0[33];

#pragma unroll 1
    for (int i = 0; i < 12; ++i) {
        // prefetch next window's 4 values
        float n0 = 0.f, n1 = 0.f, n2 = 0.f, n3 = 0.f;
        if (i < 11) {
            int ii = i + 1;
            const float* xb = xb0 + (ii >> 2) * 1024 + (((ii >> 1) & 1) << 5) + (ii & 1);
            n0 = xb[0]; n1 = xb[1]; n2 = xb[32]; n3 = xb[33];
        }
        float e[4][5];
        e[0][0] = siluf(v0); bspline4(v0, &e[0][1]);
        e[1][0] = siluf(v1); bspline4(v1, &e[1][1]);
        e[2][0] = siluf(v2); bspline4(v2, &e[2][1]);
        e[3][0] = siluf(v3); bspline4(v3, &e[3][1]);
#pragma unroll
        for (int oo = 0; oo < 16; ++oo) {
            const float* wp = &Wl[(i * 32 + obase + oo) * 8];
            float4 w0 = *(const float4*)wp;
            float w4v = wp[4];
#pragma unroll
            for (int pp = 0; pp < 4; ++pp) {
                acc[pp][oo] += e[pp][0] * w0.x + e[pp][1] * w0.y + e[pp][2] * w0.z
                             + e[pp][3] * w0.w + e[pp][4] * w4v;
            }
        }
        v0 = n0; v1 = n1; v2 = n2; v3 = n3;
    }

    float* dst = pooled + ((size_t)b * 225 + cell) * 32 + obase;
#pragma unroll 1
    for (int oo = 0; oo < 16; ++oo) {
        float a0 = acc[0][oo], a1 = acc[1][oo], a2 = acc[2][oo], a3 = acc[3][oo];
        dst[oo] = fmaxf(fmaxf(a0, a1), fmaxf(a2, a3));
        float s  = a0 + a1 + a2 + a3;
        float s2 = a0 * a0 + a1 * a1 + a2 * a2 + a3 * a3;
#pragma unroll
        for (int off = 32; off >= 2; off >>= 1) {
            s  += __shfl_down(s, off, 64);
            s2 += __shfl_down(s2, off, 64);
        }
        if (lane < 2) {
            int o = lane * 16 + oo;
            int slot = blockIdx.x * 4 + wave;
            part[(size_t)(2 * o) * NSLOT1 + slot]     = s;
            part[(size_t)(2 * o + 1) * NSLOT1 + slot] = s2;
        }
    }
}

// ---------- border patches (py==30 or px==30): stats only ----------

__global__ __launch_bounds__(256, 2) void border_kernel(
        const float* __restrict__ x, const float* __restrict__ bw,
        const float* __restrict__ sw, float* __restrict__ part) {
    __shared__ float Wl[12 * 32 * 8];
    for (int j = threadIdx.x; j < 12 * 32 * 5; j += 256) {
        int i = j / 160;
        int r = j - i * 160;
        int o = r / 5;
        int k = r - o * 5;
        Wl[(i * 32 + o) * 8 + k] = (k == 0) ? bw[o * 12 + i]
                                            : sw[(o * 12 + i) * 4 + k - 1];
    }
    __syncthreads();

    int lane = threadIdx.x & 63, wave = threadIdx.x >> 6;
    int id = blockIdx.x * 256 + threadIdx.x;
    int b = id / 61, j = id - b * 61;
    int py = (j < 31) ? 30 : (j - 31);
    int px = (j < 31) ? j : 30;

    float acc[32];
#pragma unroll
    for (int o = 0; o < 32; ++o) acc[o] = 0.f;
#pragma unroll 1
    for (int i = 0; i < 12; ++i) {
        int c = i >> 2, dy = (i >> 1) & 1, dx = i & 1;
        float v = x[(b * 3 + c) * 1024 + (py + dy) * 32 + px + dx];
        float e[5];
        e[0] = siluf(v);
        bspline4(v, &e[1]);
#pragma unroll
        for (int o = 0; o < 32; ++o) {
            const float* wp = &Wl[(i * 32 + o) * 8];
            float4 w0 = *(const float4*)wp;
            acc[o] += e[0] * w0.x + e[1] * w0.y + e[2] * w0.z
                    + e[3] * w0.w + e[4] * wp[4];
        }
    }
#pragma unroll 1
    for (int o = 0; o < 32; ++o) {
        float a = acc[o], a2 = acc[o] * acc[o];
#pragma unroll
        for (int off = 32; off > 0; off >>= 1) {
            a  += __shfl_down(a, off, 64);
            a2 += __shfl_down(a2, off, 64);
        }
        if (lane == 0) {
            int slot = 7200 + blockIdx.x * 4 + wave;
            part[(size_t)(2 * o) * NSLOT1 + slot]     = a;
            part[(size_t)(2 * o + 1) * NSLOT1 + slot] = a2;
        }
    }
}

// ---------- pre-convert conv2 weights to f16, k-layout = c*20 + s*5 + f ----------

__global__ __launch_bounds__(256) void wconv16_kernel(
        const float* __restrict__ bw, const float* __restrict__ sw,
        _Float16* __restrict__ Wf) {
    int t = blockIdx.x * 256 + threadIdx.x;
    if (t >= 64 * 640) return;
    int n = t / 640;
    int k = t - n * 640;
    int c = k / 20;
    int r = k - c * 20;
    int s = r / 5;
    int f = r - s * 5;
    float val = (f == 0) ? bw[n * 128 + c * 4 + s]
                         : sw[n * 512 + c * 16 + s * 4 + (f - 1)];
    Wf[t] = (_Float16)val;
}

// ---------- conv2 group-data prefetch ----------

__device__ __forceinline__ void c2_load(
        const float* __restrict__ pooled, const float* __restrict__ stats1,
        const float* __restrict__ g1v, const float* __restrict__ b1v,
        int c, const size_t pwoff[2], float pv[2][4], float pst[4]) {
    pst[0] = stats1[2 * c];
    pst[1] = stats1[2 * c + 1];
    pst[2] = g1v[c];
    pst[3] = b1v[c];
#pragma unroll
    for (int cc = 0; cc < 2; ++cc) {
        const float* pw = pooled + pwoff[cc] + c;
        pv[cc][0] = pw[0];
        pv[cc][1] = pw[32];
        pv[cc][2] = pw[480];
        pv[cc][3] = pw[512];
    }
}

// ---------- conv2 (fp16 MFMA, barrier-free, single-buffer, pipelined) ----------
// Single Eh buffer (21.5 KB): same-wave in-order LDS ops make both the
// write->read (validated r8) and read->next-write orderings safe without
// __syncthreads. Group g+1's pooled/BN loads are issued before group g's
// expansion+MFMA to hide global latency.

#define C2_LDW 168

__global__ __launch_bounds__(256, 5) void conv2_kernel(
        const float* __restrict__ pooled, const float* __restrict__ stats1,
        const float* __restrict__ g1v, const float* __restrict__ b1v,
        const _Float16* __restrict__ Wf, float* __restrict__ Pt,
        float* __restrict__ part) {
    __shared__ _Float16 Eh[64 * C2_LDW];

    int t = threadIdx.x;
    int lane = t & 63, wv = t >> 6;
    int quad = lane >> 4, l15 = lane & 15;

    int cl = lane & 7;           // channel within group (8 per group)
    int rl = lane >> 3;          // 0..7; rows rl and rl+8 of this wave's tile
    int m[2];
    size_t pwoff[2];
#pragma unroll
    for (int cc = 0; cc < 2; ++cc) {
        m[cc] = wv * 16 + rl + 8 * cc;
        int patch = blockIdx.x * 64 + m[cc];
        int pb = patch / 196;
        int q = patch - pb * 196;
        int py = q / 14;
        int px = q - py * 14;
        pwoff[cc] = ((size_t)pb * 225 + py * 15 + px) * 32;
    }
    const float invN1 = 1.0f / (1024.0f * 961.0f);

    f32x4 acc[4];
#pragma unroll
    for (int nt = 0; nt < 4; ++nt) acc[nt] = (f32x4){0.f, 0.f, 0.f, 0.f};

    float pv[2][4], pst[4];
    c2_load(pooled, stats1, g1v, b1v, cl, pwoff, pv, pst);

#pragma unroll 1
    for (int g = 0; g < 4; ++g) {
        float mean = pst[0] * invN1;
        float var  = pst[1] * invN1 - mean * mean;
        float sc = rsqrtf(var + BN_EPS) * pst[2];
        float sh = pst[3] - mean * sc;
        float cv[2][4];
#pragma unroll
        for (int cc = 0; cc < 2; ++cc)
#pragma unroll
            for (int s = 0; s < 4; ++s)
                cv[cc][s] = fmaxf(pv[cc][s] * sc + sh, 0.f);
        // prefetch next group's pooled/BN data (uses are next iteration)
        if (g < 3)
            c2_load(pooled, stats1, g1v, b1v, (g + 1) * 8 + cl, pwoff, pv, pst);
        // ---- build this wave's 16 E rows (fp16), 2 cells per lane ----
#pragma unroll
        for (int cc = 0; cc < 2; ++cc) {
            float f[20];
#pragma unroll
            for (int s = 0; s < 4; ++s) {
                float v = cv[cc][s];
                f[s * 5] = siluf(v);
                bspline4(v, &f[s * 5 + 1]);
            }
            int* dst = (int*)&Eh[m[cc] * C2_LDW + cl * 20];
#pragma unroll
            for (int i = 0; i < 10; ++i) {
                union { _Float16 h[2]; int i32; } u;
                u.h[0] = (_Float16)f[2 * i];
                u.h[1] = (_Float16)f[2 * i + 1];
                dst[i] = u.i32;
            }
        }
        // ---- MFMA (no barrier: rows wv*16..+15 written by this wave) ----
#pragma unroll
        for (int ks = 0; ks < 5; ++ks) {
            int ko = ks * 32 + quad * 8;
            f16x8 a = *(const f16x8*)&Eh[(wv * 16 + l15) * C2_LDW + ko];
#pragma unroll
            for (int nt = 0; nt < 4; ++nt) {
                f16x8 bf = *(const f16x8*)&Wf[(size_t)(nt * 16 + l15) * 640
                                              + g * 160 + ko];
                acc[nt] = __builtin_amdgcn_mfma_f32_16x16x32_f16(a, bf, acc[nt], 0, 0, 0);
            }
        }
    }

    // ---- store: rows wv*16 + quad*4 + reg, cols nt*16 + l15 ----
    int rowb = blockIdx.x * 64 + wv * 16 + quad * 4;
#pragma unroll
    for (int nt = 0; nt < 4; ++nt) {
        int o = nt * 16 + l15;
#pragma unroll
        for (int reg = 0; reg < 4; ++reg)
            Pt[(size_t)(rowb + reg) * 64 + o] = acc[nt][reg];
    }
    // ---- fused stats over this wave's 16 rows ----
    float s[4], s2[4];
#pragma unroll
    for (int nt = 0; nt < 4; ++nt) {
        float a0 = acc[nt][0], a1 = acc[nt][1], a2v = acc[nt][2], a3 = acc[nt][3];
        s[nt]  = a0 + a1 + a2v + a3;
        s2[nt] = a0 * a0 + a1 * a1 + a2v * a2v + a3 * a3;
    }
#pragma unroll
    for (int nt = 0; nt < 4; ++nt) {
        s[nt]  += __shfl_down(s[nt], 16, 64);
        s2[nt] += __shfl_down(s2[nt], 16, 64);
        s[nt]  += __shfl_down(s[nt], 32, 64);
        s2[nt] += __shfl_down(s2[nt], 32, 64);
    }
    if (lane < 16) {
        int slot = blockIdx.x * 4 + wv;
#pragma unroll
        for (int nt = 0; nt < 4; ++nt) {
            int o = nt * 16 + l15;
            part[(size_t)(2 * o) * NSLOT2 + slot]     = s[nt];
            part[(size_t)(2 * o + 1) * NSLOT2 + slot] = s2[nt];
        }
    }
}

// ---------- reduce per-wave partials -> stats ----------

__global__ __launch_bounds__(256) void redstats_kernel(
        const float* __restrict__ part, float* __restrict__ stats, int nblk) {
    int p = blockIdx.x;
    const float* src = part + (size_t)p * nblk;
    float s = 0.f;
    for (int j = threadIdx.x; j < nblk; j += 256) s += src[j];
#pragma unroll
    for (int off = 32; off > 0; off >>= 1) s += __shfl_down(s, off, 64);
    __shared__ float ls[4];
    if ((threadIdx.x & 63) == 0) ls[threadIdx.x >> 6] = s;
    __syncthreads();
    if (threadIdx.x == 0) stats[p] = ls[0] + ls[1] + ls[2] + ls[3];
}

// ---------- stage-2 BN + ReLU + pool from Pt [patch][64] -> pooled2 [b][q2*64+c] ----------

__global__ __launch_bounds__(256) void bnpool2_kernel(
        const float* __restrict__ Pt, const float* __restrict__ stats,
        const float* __restrict__ g, const float* __restrict__ bb,
        float* __restrict__ out) {
    int t = blockIdx.x * 256 + threadIdx.x;
    if (t >= 1024 * 49 * 64) return;
    int c  = t & 63;
    int q2 = (t >> 6) % 49;
    int b  = t / (49 * 64);
    float mean = stats[2 * c] * (1.0f / 200704.0f);
    float var  = stats[2 * c + 1] * (1.0f / 200704.0f) - mean * mean;
    float sc = rsqrtf(var + BN_EPS) * g[c];
    float sh = bb[c] - mean * sc;
    int py2 = q2 / 7, px2 = q2 - py2 * 7;
    int q = (py2 * 2) * 14 + px2 * 2;
    const float* p = Pt + ((size_t)b * 196 + q) * 64 + c;
    float v0 = fmaxf(p[0] * sc + sh, 0.f);
    float v1 = fmaxf(p[64] * sc + sh, 0.f);
    float v2 = fmaxf(p[14 * 64] * sc + sh, 0.f);
    float v3 = fmaxf(p[15 * 64] * sc + sh, 0.f);
    out[t] = fmaxf(fmaxf(v0, v1), fmaxf(v2, v3));
}

// ---------- transpose fc1_w into wT[(q2*64 + c)*64 + o] ----------

__global__ __launch_bounds__(256) void transpose_kernel(
        const float* __restrict__ w, float* __restrict__ wT) {
    int t = blockIdx.x * 256 + threadIdx.x;
    if (t >= 64 * 3136) return;
    int o = t & 63;
    int m = t >> 6;
    int c = m & 63;
    int q2 = m >> 6;
    wT[(size_t)m * 64 + o] = w[(size_t)o * 3136 + c * 49 + q2];
}

// ---------- fc1: pooled2 flat [1024,3136] @ wT -> z [1024,64] ----------

__global__ __launch_bounds__(256) void fc1_kernel(
        const float* __restrict__ xin, const float* __restrict__ wT,
        const float* __restrict__ bias, float* __restrict__ z) {
    __shared__ float xs[4 * 3136];
    __shared__ float red[4][4][64];
    int b0 = blockIdx.x * 4;
    for (int j = threadIdx.x; j < 4 * 3136; j += 256)
        xs[j] = xin[(size_t)b0 * 3136 + j];
    __syncthreads();
    int o = threadIdx.x & 63, q = threadIdx.x >> 6;
    float s0 = 0.f, s1 = 0.f, s2 = 0.f, s3 = 0.f;
    for (int j = q * 784; j < q * 784 + 784; ++j) {
        float wv = wT[(size_t)j * 64 + o];
        s0 += xs[j] * wv;
        s1 += xs[3136 + j] * wv;
        s2 += xs[2 * 3136 + j] * wv;
        s3 += xs[3 * 3136 + j] * wv;
    }
    red[0][q][o] = s0; red[1][q][o] = s1; red[2][q][o] = s2; red[3][q][o] = s3;
    __syncthreads();
    int bb = threadIdx.x >> 6;
    float tot = red[bb][0][o] + red[bb][1][o] + red[bb][2][o] + red[bb][3][o] + bias[o];
    z[((size_t)(b0 + bb)) * 64 + o] = tot;
}

// ---------- bn1d column stats over z [1024,64] ----------

__global__ __launch_bounds__(256) void colstats_kernel(
        const float* __restrict__ z, float* __restrict__ stats) {
    int c = blockIdx.x;
    float s = 0.f, s2 = 0.f;
    for (int b = threadIdx.x; b < 1024; b += 256) {
        float v = z[(size_t)b * 64 + c];
        s += v; s2 += v * v;
    }
#pragma unroll
    for (int off = 32; off > 0; off >>= 1) {
        s  += __shfl_down(s, off, 64);
        s2 += __shfl_down(s2, off, 64);
    }
    __shared__ float ls[8];
    int w = threadIdx.x >> 6;
    if ((threadIdx.x & 63) == 0) { ls[w * 2] = s; ls[w * 2 + 1] = s2; }
    __syncthreads();
    if (threadIdx.x == 0) {
        stats[2 * c]     = ls[0] + ls[2] + ls[4] + ls[6];
        stats[2 * c + 1] = ls[1] + ls[3] + ls[5] + ls[7];
    }
}

// ---------- final: bn1d + relu + fc2 -> out [1024,10] ----------

__global__ __launch_bounds__(256) void final_kernel(
        const float* __restrict__ z, const float* __restrict__ stats,
        const float* __restrict__ g, const float* __restrict__ bb,
        const float* __restrict__ w2, const float* __restrict__ b2,
        float* __restrict__ out) {
    int t = blockIdx.x * 256 + threadIdx.x;
    if (t >= 10240) return;
    int o = t % 10, b = t / 10;
    float acc = b2[o];
#pragma unroll 8
    for (int c = 0; c < 64; ++c) {
        float mean = stats[2 * c] * (1.0f / 1024.0f);
        float var  = stats[2 * c + 1] * (1.0f / 1024.0f) - mean * mean;
        float sc = rsqrtf(var + BN_EPS) * g[c];
        float a = fmaxf(z[(size_t)b * 64 + c] * sc + (bb[c] - mean * sc), 0.f);
        acc += a * w2[o * 64 + c];
    }
    out[t] = acc;
}

// ---------- launch ----------

extern "C" void kernel_launch(void* const* d_in, const int* in_sizes, int n_in,
                              void* d_out, int out_size, void* d_ws, size_t ws_size,
                              hipStream_t stream) {
    const float* x   = (const float*)d_in[0];
    const float* bw1 = (const float*)d_in[1];
    const float* sw1 = (const float*)d_in[2];
    const float* g1  = (const float*)d_in[3];
    const float* b1  = (const float*)d_in[4];
    const float* bw2 = (const float*)d_in[5];
    const float* sw2 = (const float*)d_in[6];
    const float* g2  = (const float*)d_in[7];
    const float* b2v = (const float*)d_in[8];
    const float* fw1 = (const float*)d_in[9];
    const float* fb1 = (const float*)d_in[10];
    const float* g3  = (const float*)d_in[11];
    const float* b3  = (const float*)d_in[12];
    const float* fw2 = (const float*)d_in[13];
    const float* fb2 = (const float*)d_in[14];
    float* out = (float*)d_out;

    char* ws = (char*)d_ws;
    // region A [0, 58 MB): part1 (2.1 MB) during conv1 (dead after redstats1),
    //   then Pt [200704][64] (51.38 MB) + part2 at +51,380,224 (6.4 MB)
    float* part1  = (float*)(ws);
    float* Pt     = (float*)(ws);
    float* part2  = (float*)(ws + 51380224);
    // Wf (80 KB) in the dead gap between region A and region B
    _Float16* Wf  = (_Float16*)(ws + 100000000);
    // region B: pooled raw [1024][225][32] (29.5 MB); later pooled2 [1024,3136]
    float* pooled = (float*)(ws + 125960192);
    float* z      = (float*)(ws + 155451392);   // [1024,64]
    float* wT     = (float*)(ws + 155713536);   // [3136,64]
    float* stats1 = (float*)(ws + 156516352);   // 64 floats
    float* stats2 = (float*)(ws + 156516608);   // 128 floats
    float* stats3 = (float*)(ws + 156517120);   // 128 floats

    transpose_kernel<<<(64 * 3136 + 255) / 256, 256, 0, stream>>>(fw1, wT);
    wconv16_kernel<<<160, 256, 0, stream>>>(bw2, sw2, Wf);

    conv1_kernel<<<1800, 256, 0, stream>>>(x, bw1, sw1, pooled, part1);
    border_kernel<<<244, 256, 0, stream>>>(x, bw1, sw1, part1);
    redstats_kernel<<<64, 256, 0, stream>>>(part1, stats1, NSLOT1);

    conv2_kernel<<<3136, 256, 0, stream>>>(pooled, stats1, g1, b1,
                                           Wf, Pt, part2);
    redstats_kernel<<<128, 256, 0, stream>>>(part2, stats2, NSLOT2);

    float* pooled2 = pooled;  // region B reuse (pooled raw dead after conv2)
    bnpool2_kernel<<<(1024 * 49 * 64 + 255) / 256, 256, 0, stream>>>(
        Pt, stats2, g2, b2v, pooled2);

    fc1_kernel<<<256, 256, 0, stream>>>(pooled2, wT, fb1, z);
    colstats_kernel<<<64, 256, 0, stream>>>(z, stats3);
    final_kernel<<<(10240 + 255) / 256, 256, 0, stream>>>(z, stats3, g3, b3, fw2, fb2, out);
}